// Round 11
// baseline (260.332 us; speedup 1.0000x reference)
//
#include <hip/hip_runtime.h>
#include <hip/hip_bf16.h>

// MetaQDA MAP. D=640, C=64, N=1024, Q=2048, REG=0.3.
// sigma_c*denom = L L^T + U_c J_c U_c^T (rank 18) => Woodbury.
// Round 16: R15's L2-direct gram failed (post-timing absmax 40960) AND was
// slower -> LDS-staged gram (24576-stable) is the only safe form; R14=214us
// is the base. k_gv re-derived: gram blocks bid<64 pile 3-per-CU (round-
// robin dispatch x 3-blocks/CU LDS cap) and the thread-per-pair dot phase
// (all lanes at same d, 18 rows -> (r+d)%8 slot collisions = the exact
// 1.91M conflict count) triples on shared LDS. Fixes (gram only):
//  (1) gram classes at bid%18==0 -> one gram block per CU.
//  (2) dot phase = R0's wave-parallel form: lanes read sv[i][lane+64k]
//      (stride-1, conflict-free) + butterfly -- R0's exact arithmetic
//      (absmax 24576 measured). GEMMs/staging/GJ byte-identical to R14.
// Gram stays fp32 (round-6 post-mortem: bf16 Gram -> absmax 1.8e7).

#define D 640
#define C 64
#define NSUP 1024
#define Q 2048
#define KMAX 16
#define R18 18           // Woodbury rank: 1 (m) + 16 (x) + 1 (mu)
#define VROWS (C * R18)  // 1152
#define YROWS 3137       // 2048 Xq + 1024 X + 1 m + 64 mu
#define YPAD 3200
#define NEXT 704         // 640 tilde cols + 64 ip0 cols

typedef __attribute__((ext_vector_type(8))) short bf16x8;
typedef __attribute__((ext_vector_type(4))) float floatx4;

__device__ __forceinline__ unsigned short f2bf(float x) {
    unsigned int u = __float_as_uint(x);
    unsigned int r = u + 0x7FFFu + ((u >> 16) & 1u);
    return (unsigned short)(r >> 16);
}

__device__ __forceinline__ void pack4(const float* vv, unsigned short* hp, unsigned short* lp) {
#pragma unroll
    for (int i = 0; i < 4; ++i) {
        unsigned short hb = f2bf(vv[i]);
        float hf = __uint_as_float((unsigned int)hb << 16);
        hp[i] = hb;
        lp[i] = f2bf(vv[i] - hf);
    }
}

__device__ __forceinline__ void rownorm_body(const float* __restrict__ A, int ld,
                                             float* __restrict__ out, int gw, int lane) {
    const float* row = A + (size_t)gw * ld;
    float s = 0.f;
    for (int d = lane; d < D; d += 64) { float v = row[d]; s += v * v; }
#pragma unroll
    for (int off = 32; off; off >>= 1) s += __shfl_xor(s, off);
    if (lane == 0) out[gw] = s;
}

// bijective chunked XCD swizzle (m204): round-robin pos -> contiguous chunk
__device__ __forceinline__ int xcd_chunk(int orig, int nwg) {
    int q = nwg >> 3, r = nwg & 7;
    int xcd = orig & 7, pos = orig >> 3;
    return (xcd < r) ? xcd * (q + 1) + pos
                     : r * (q + 1) + (xcd - r) * q + pos;
}

// ---------------- setup (block 0) + zero Bh/Bl[0:640] & Ah/Al pad rows ---
#define BZCH (640 * 640 / 8)          // 51200 16B-chunks per B array
#define AZCH (63 * 640 / 8)           // 5040 16B-chunks per A pad region
__global__ void k_setup(const int* __restrict__ y, const float* __restrict__ kappa,
                        const float* __restrict__ nu, const float* __restrict__ diag,
                        int* __restrict__ cnt, int* __restrict__ idx,
                        float* __restrict__ sc, float* __restrict__ rd,
                        int* __restrict__ rowmap,
                        unsigned short* __restrict__ Ah, unsigned short* __restrict__ Al,
                        unsigned short* __restrict__ Bh, unsigned short* __restrict__ Bl) {
    int tid = threadIdx.x;
    if (blockIdx.x > 0) {
        int id = (blockIdx.x - 1) * 256 + tid;
        const uint4 z = {0u, 0u, 0u, 0u};
        if (id < BZCH) ((uint4*)Bh)[id] = z;
        else if (id < 2 * BZCH) ((uint4*)Bl)[id - BZCH] = z;
        else if (id < 2 * BZCH + AZCH) ((uint4*)(Ah + (size_t)YROWS * D))[id - 2 * BZCH] = z;
        else if (id < 2 * BZCH + 2 * AZCH) ((uint4*)(Al + (size_t)YROWS * D))[id - 2 * BZCH - AZCH] = z;
        return;
    }
    __shared__ int lc[C];
    if (tid < C) lc[tid] = 0;
    __syncthreads();
    for (int n = tid; n < NSUP; n += 256) {
        int c = y[n];
        int k = atomicAdd(&lc[c], 1);
        if (k < KMAX) idx[c * KMAX + k] = n;
    }
    __syncthreads();
    for (int d = tid; d < D; d += 256) rd[d] = 1.0f / fabsf(diag[d]);
    if (tid < C) {
        int n = lc[tid]; if (n > KMAX) n = KMAX;
        cnt[tid] = n;
        float kap = fabsf(kappa[0]) + 1e-6f;
        float nuv = fmaxf(nu[0], (float)(D - 1) + 1e-6f);
        float Ncf = (float)n;
        sc[64 + tid]  = Ncf / (kap + Ncf);            // w_c
        sc[128 + tid] = nuv + Ncf + (float)(D + 2);   // denom_c
        sc[192 + tid] = -1.0f / (kap + Ncf);          // J^{-1} last diag
        if (tid == 0) { sc[0] = kap; sc[1] = nuv; }
    }
    __syncthreads();
    for (int i = tid; i < VROWS; i += 256) {
        int c = i / R18, j = i - c * R18;
        int nc = lc[c] < KMAX ? lc[c] : KMAX;
        int rm;
        if (j == 0) rm = Q + NSUP;                       // m~
        else if (j <= KMAX) rm = (j - 1 < nc) ? Q + idx[c * KMAX + j - 1] : -1;
        else rm = Q + NSUP + 1 + c;                      // mu~
        rowmap[i] = rm;
    }
}

// ---------------- fused: dinv + mu + pack(Xq,X,m) + a0 -------------------
__global__ __launch_bounds__(256) void k_dinv_mu(
        const float* __restrict__ tlow, const float* __restrict__ rd,
        float* __restrict__ Linv,
        const float* __restrict__ X, const float* __restrict__ m,
        const int* __restrict__ cnt, const int* __restrict__ idx,
        const float* __restrict__ sc, float* __restrict__ mu,
        const float* __restrict__ Xq,
        unsigned short* __restrict__ Ah, unsigned short* __restrict__ Al,
        unsigned short* __restrict__ Bh, unsigned short* __restrict__ Bl,
        float* __restrict__ a0) {
    __shared__ float Lst[128 * 128];
    int tid = threadIdx.x;
    int bid = blockIdx.x;
    if (bid < 160) {
        int b = bid >> 5;
        int j = ((bid & 31) << 2) + (tid >> 6);
        int lane = tid & 63;
        int bB = b * 128;
        {
            float4 tv[16];
            float rv[16];
#pragma unroll
            for (int u = 0; u < 16; ++u) {
                int e = tid + u * 256;              // e = r*32 + c4/4, covers 128x32
                int c4 = (e & 31) * 4, r = e >> 5;
                tv[u] = *(const float4*)(tlow + (size_t)(bB + r) * D + bB + c4);
                rv[u] = rd[bB + r];
            }
#pragma unroll
            for (int u = 0; u < 16; ++u) {
                int e = tid + u * 256;
                int c4 = (e & 31) * 4, r = e >> 5;
                float vv[4] = {tv[u].x, tv[u].y, tv[u].z, tv[u].w};
#pragma unroll
                for (int t = 0; t < 4; ++t) {
                    int c = c4 + t;
                    float v;
                    if (r == c) v = 1.0f;
                    else if (r > c) v = rv[u] * vv[t];
                    else v = 0.f;
                    Lst[c * 128 + (r ^ (c & 63))] = v;
                }
            }
        }
        __syncthreads();
        float rd0 = rd[bB + lane], rd1 = rd[bB + 64 + lane];
        float acc0 = 0.f, acc1 = 0.f, zz0 = 0.f, zz1 = 0.f;
        for (int i = j; i < 128; ++i) {
            int ri = i >> 6, il = i & 63;
            float av = (ri == 0) ? acc0 : acc1;
            float ai = __shfl(av, il);
            float zi = (i == j) ? __shfl((ri == 0) ? rd0 : rd1, il) : -ai;
            int sw = i & 63;
            float l0 = Lst[i * 128 + (lane ^ sw)];
            float l1 = Lst[i * 128 + 64 + (lane ^ sw)];
            if (lane > i) acc0 += l0 * zi;
            if (64 + lane > i) acc1 += l1 * zi;
            if (lane == i) zz0 = zi;
            if (64 + lane == i) zz1 = zi;
        }
        Linv[(size_t)(bB + lane) * D + bB + j] = zz0;
        Linv[(size_t)(bB + 64 + lane) * D + bB + j] = zz1;
        unsigned short h0 = f2bf(zz0);
        float hf0 = __uint_as_float((unsigned int)h0 << 16);
        Bh[(size_t)(bB + lane) * D + bB + j] = h0;
        Bl[(size_t)(bB + lane) * D + bB + j] = f2bf(zz0 - hf0);
        unsigned short h1 = f2bf(zz1);
        float hf1 = __uint_as_float((unsigned int)h1 << 16);
        Bh[(size_t)(bB + 64 + lane) * D + bB + j] = h1;
        Bl[(size_t)(bB + 64 + lane) * D + bB + j] = f2bf(zz1 - hf1);
    } else if (bid < 320) {
        int u = (bid - 160) * 2 + (tid >> 7);     // 0..319
        int c = u / 5, by = u - c * 5;
        int d = by * 128 + (tid & 127);
        int n = cnt[c];
        float s = 0.f;
        for (int k = 0; k < n; ++k) s += X[(size_t)idx[c * KMAX + k] * D + d];
        float w = sc[64 + c];
        float mean = (n > 0) ? s / (float)n : 0.f;
        float val = (1.f - w) * m[d] + w * mean;
        mu[(size_t)c * D + d] = val;
        unsigned short hb = f2bf(val);
        float hf = __uint_as_float((unsigned int)hb << 16);
        unsigned short lb = f2bf(val - hf);
        Ah[(size_t)(Q + NSUP + 1 + c) * D + d] = hb;   // A row 3073+c
        Al[(size_t)(Q + NSUP + 1 + c) * D + d] = lb;
        Bh[(size_t)(D + c) * D + d] = hb;              // B row 640+c
        Bl[(size_t)(D + c) * D + d] = lb;
    } else if (bid < 2240) {
        int gid = (bid - 320) * 256 + tid;             // rows 0..3071
        int row = gid / 160, c = (gid - row * 160) * 4;
        float4 v = (row < Q) ? *(const float4*)(Xq + (size_t)row * D + c)
                             : *(const float4*)(X + (size_t)(row - Q) * D + c);
        float vv[4] = {v.x, v.y, v.z, v.w};
        ushort4 h, l;
        pack4(vv, (unsigned short*)&h, (unsigned short*)&l);
        *(ushort4*)(Ah + (size_t)row * D + c) = h;
        *(ushort4*)(Al + (size_t)row * D + c) = l;
    } else if (bid == 2240) {
        if (tid < 160) {
            int c = tid * 4;
            float4 v = *(const float4*)(m + c);
            float vv[4] = {v.x, v.y, v.z, v.w};
            ushort4 h, l;
            pack4(vv, (unsigned short*)&h, (unsigned short*)&l);
            *(ushort4*)(Ah + (size_t)(Q + NSUP) * D + c) = h;   // row 3072
            *(ushort4*)(Al + (size_t)(Q + NSUP) * D + c) = l;
        }
    } else {
        int gw = ((bid - 2241) * 256 + tid) >> 6;      // 0..2047
        rownorm_body(Xq, D, a0, gw, tid & 63);
    }
}

// ---------------- Lhat_ik = Dinv_i * L_ik (strict-lower blocks) ----------
__global__ void k_lhat(const float* __restrict__ tlow, const float* __restrict__ Linv,
                       float* __restrict__ Lhat) {
    const int bi_tab[10] = {1, 2, 2, 3, 3, 3, 4, 4, 4, 4};
    const int bk_tab[10] = {0, 0, 1, 0, 1, 2, 0, 1, 2, 3};
    int p = blockIdx.y;
    int bi = bi_tab[p], bk = bk_tab[p];
    int tid = threadIdx.x;
    int c = tid & 127;
    int r = (blockIdx.x << 1) + (tid >> 7);
    const float* drow = Linv + (size_t)(bi * 128 + r) * D + bi * 128;
    const float* lcol = tlow + (size_t)(bi * 128) * D + bk * 128 + c;
    float s = 0.f;
#pragma unroll 4
    for (int t = 0; t < 128; ++t) s += drow[t] * lcol[(size_t)t * D];
    Lhat[(size_t)(bi * 128 + r) * D + bk * 128 + c] = s;
}

// ---------------- Linv off-diag: right-looking strip recurrence ----------
template<int B>
__device__ __forceinline__ void linv_chain(const float* __restrict__ Lhat,
                                           float* __restrict__ Linv,
                                           unsigned short* __restrict__ Bh,
                                           unsigned short* __restrict__ Bl,
                                           float S[4][128][20],
                                           int cB, int tid) {
    const int ty = tid >> 2, tx = tid & 3;   // rows {2ty,2ty+1}, cols 4tx..4tx+3
    const int r0 = 2 * ty;
    float acc[4 - B][2][4];
#pragma unroll
    for (int a = 0; a < 4 - B; ++a)
#pragma unroll
        for (int rr = 0; rr < 2; ++rr)
#pragma unroll
            for (int cc = 0; cc < 4; ++cc) acc[a][rr][cc] = 0.f;
#pragma unroll
    for (int js = 0; js < 4 - B; ++js) {     // contraction block j = B + js
        const int j = B + js;
        for (int k0 = 0; k0 < 128; k0 += 8) {
            float svf[8][4];
#pragma unroll
            for (int u = 0; u < 8; ++u) {
                float4 s4 = *(const float4*)&S[js][k0 + u][tx * 4];
                svf[u][0] = s4.x; svf[u][1] = s4.y; svf[u][2] = s4.z; svf[u][3] = s4.w;
            }
#pragma unroll
            for (int a = js; a < 4 - B; ++a) {   // output block i = B + 1 + a
                const int i = B + 1 + a;
                const float* p0 = Lhat + (size_t)(i * 128 + r0) * D + j * 128 + k0;
                const float* p1 = p0 + D;
                float4 a00 = *(const float4*)(p0);
                float4 a01 = *(const float4*)(p0 + 4);
                float4 a10 = *(const float4*)(p1);
                float4 a11 = *(const float4*)(p1 + 4);
                float ar0[8] = {a00.x, a00.y, a00.z, a00.w, a01.x, a01.y, a01.z, a01.w};
                float ar1[8] = {a10.x, a10.y, a10.z, a10.w, a11.x, a11.y, a11.z, a11.w};
#pragma unroll
                for (int u = 0; u < 8; ++u) {
#pragma unroll
                    for (int cc = 0; cc < 4; ++cc) {
                        acc[a][0][cc] += ar0[u] * svf[u][cc];
                        acc[a][1][cc] += ar1[u] * svf[u][cc];
                    }
                }
            }
        }
        {
            const int i = j + 1;
#pragma unroll
            for (int rr = 0; rr < 2; ++rr) {
                const int r = r0 + rr;
                float vv[4];
#pragma unroll
                for (int cc = 0; cc < 4; ++cc) vv[cc] = -acc[js][rr][cc];
                float4 v = {vv[0], vv[1], vv[2], vv[3]};
                if (js + 1 < 4 - B) *(float4*)&S[js + 1][r][tx * 4] = v;
                *(float4*)(Linv + (size_t)(i * 128 + r) * D + cB + tx * 4) = v;
                ushort4 hh, ll;
                pack4(vv, (unsigned short*)&hh, (unsigned short*)&ll);
                *(ushort4*)(Bh + (size_t)(i * 128 + r) * D + cB + tx * 4) = hh;
                *(ushort4*)(Bl + (size_t)(i * 128 + r) * D + cB + tx * 4) = ll;
            }
        }
        if (js + 1 < 4 - B) __syncthreads();
    }
}

__global__ __launch_bounds__(256) void k_linv_fill(const float* __restrict__ Lhat,
                                                   float* __restrict__ Linv,
                                                   unsigned short* __restrict__ Bh,
                                                   unsigned short* __restrict__ Bl) {
    __shared__ __align__(16) float S[4][128][20];   // 40 KB
    int tid = threadIdx.x;
    int b = blockIdx.x >> 3, strip = blockIdx.x & 7;
    int bB = b * 128, cB = bB + strip * 16;
    {   // load S[0] strip from the Dinv block already in Linv
        int r = tid >> 1, c0 = (tid & 1) * 8;
        const float* src = Linv + (size_t)(bB + r) * D + cB + c0;
        *(float4*)&S[0][r][c0]     = *(const float4*)(src);
        *(float4*)&S[0][r][c0 + 4] = *(const float4*)(src + 4);
    }
    __syncthreads();
    if (b == 0)      linv_chain<0>(Lhat, Linv, Bh, Bl, S, cB, tid);
    else if (b == 1) linv_chain<1>(Lhat, Linv, Bh, Bl, S, cB, tid);
    else if (b == 2) linv_chain<2>(Lhat, Linv, Bh, Bl, S, cB, tid);
    else             linv_chain<3>(Lhat, Linv, Bh, Bl, S, cB, tid);
}

// ---------------- split-bf16 MFMA NT GEMM, 64x64 tile --------------------
// R11 structure (LDS-staged, 2 barriers/step) + chunked XCD swizzle (T1).
// If Th != nullptr, epilogue also writes the bf16 split for cols < 640.
__global__ __launch_bounds__(256) void k_mfma_nt(
        const unsigned short* __restrict__ Ah, const unsigned short* __restrict__ Al,
        const unsigned short* __restrict__ Bh, const unsigned short* __restrict__ Bl,
        float* __restrict__ Out, int M, int N, int ldo,
        unsigned short* __restrict__ Th, unsigned short* __restrict__ Tl) {
    __shared__ unsigned short Ah_s[64 * 32], Al_s[64 * 32];
    __shared__ unsigned short Bh_s[64 * 32], Bl_s[64 * 32];
    int tid = threadIdx.x;
    int nbx = gridDim.x, nwg = nbx * gridDim.y;
    int orig = blockIdx.y * nbx + blockIdx.x;
    int wgid = xcd_chunk(orig, nwg);                 // contiguous chunk per XCD
    int rowBase = (wgid / nbx) * 64, colBase = (wgid % nbx) * 64;
    int r = tid >> 2, e = (tid & 3) << 3;
    int gr = rowBase + r;
    int gc = colBase + r;
    bool aok = (gr < M), bok = (gc < N);
    int w = tid >> 6, lane = tid & 63, q = lane >> 4, lr = lane & 15;
    int aoff = (16 * w + lr) * 32 + q * 8;
    const uint4 z4 = {0u, 0u, 0u, 0u};
    floatx4 acc[4] = {{0.f, 0.f, 0.f, 0.f}, {0.f, 0.f, 0.f, 0.f},
                      {0.f, 0.f, 0.f, 0.f}, {0.f, 0.f, 0.f, 0.f}};
    for (int kk = 0; kk < D; kk += 32) {
        uint4 vah = aok ? *(const uint4*)(Ah + (size_t)gr * D + kk + e) : z4;
        uint4 val = aok ? *(const uint4*)(Al + (size_t)gr * D + kk + e) : z4;
        uint4 vbh = bok ? *(const uint4*)(Bh + (size_t)gc * D + kk + e) : z4;
        uint4 vbl = bok ? *(const uint4*)(Bl + (size_t)gc * D + kk + e) : z4;
        __syncthreads();
        *(uint4*)(Ah_s + r * 32 + e) = vah;
        *(uint4*)(Al_s + r * 32 + e) = val;
        *(uint4*)(Bh_s + r * 32 + e) = vbh;
        *(uint4*)(Bl_s + r * 32 + e) = vbl;
        __syncthreads();
        bf16x8 ah = *(const bf16x8*)(Ah_s + aoff);
        bf16x8 al = *(const bf16x8*)(Al_s + aoff);
#pragma unroll
        for (int tt = 0; tt < 4; ++tt) {
            int boff = (16 * tt + lr) * 32 + q * 8;
            bf16x8 bh = *(const bf16x8*)(Bh_s + boff);
            bf16x8 bl = *(const bf16x8*)(Bl_s + boff);
            acc[tt] = __builtin_amdgcn_mfma_f32_16x16x32_bf16(ah, bh, acc[tt], 0, 0, 0);
            acc[tt] = __builtin_amdgcn_mfma_f32_16x16x32_bf16(ah, bl, acc[tt], 0, 0, 0);
            acc[tt] = __builtin_amdgcn_mfma_f32_16x16x32_bf16(al, bh, acc[tt], 0, 0, 0);
        }
    }
#pragma unroll
    for (int tt = 0; tt < 4; ++tt) {
        int gc2 = colBase + 16 * tt + lr;
#pragma unroll
        for (int rg = 0; rg < 4; ++rg) {
            int gr2 = rowBase + 16 * w + q * 4 + rg;
            if (gr2 < M && gc2 < N) {
                float v = acc[tt][rg];
                Out[(size_t)gr2 * ldo + gc2] = v;
                if (Th && gc2 < D) {
                    unsigned short hb = f2bf(v);
                    float hf = __uint_as_float((unsigned int)hb << 16);
                    Th[(size_t)gr2 * D + gc2] = hb;
                    Tl[(size_t)gr2 * D + gc2] = f2bf(v - hf);
                }
            }
        }
    }
}

// ---------------- fused: gram_inv (64) + G GEMM (576) + at (512) ---------
// Gram classes at bid%18==0 (one per CU); others: slot = bid-1-bid/18,
// GEMM if slot<576 else at-rownorm. Gram dot phase = R0 wave-parallel
// (stride-1 lane reads, conflict-free) with R0's exact arithmetic.
__global__ __launch_bounds__(256) void k_gv(
        const unsigned short* __restrict__ Th, const unsigned short* __restrict__ Tl,
        const int* __restrict__ rowmap, float* __restrict__ G,
        const float* __restrict__ Yt, const float* __restrict__ mu,
        const float* __restrict__ sc, float* __restrict__ at,
        float* __restrict__ h, float* __restrict__ btil,
        float* __restrict__ b0, float* __restrict__ kinv) {
    __shared__ __align__(16) char smem[49344];
    int bid = blockIdx.x, tid = threadIdx.x;
    if (bid % 18 == 0) {
        // ---- per-class fp32 Gram (LDS-staged) + 1-wave GJ ----
        float (*sv)[644] = (float(*)[644])smem;                 // 46368 B
        float (*aug)[40] = (float(*)[40])(smem + 46368);        //  2880 B
        int* rmv = (int*)(smem + 46368 + 2880);                 //    72 B
        int c = bid / 18;
        if (tid < R18) rmv[tid] = rowmap[c * R18 + tid];
        __syncthreads();
        {   // batched staging: 12 independent float4 loads per thread
            int rmu[12];
#pragma unroll
            for (int u = 0; u < 12; ++u) {
                int i = tid + u * 256;
                int r = i / 160;
                rmu[u] = (i < R18 * 160) ? rmv[r] : -1;
            }
            float4 buf[12];
            const float4 z = {0.f, 0.f, 0.f, 0.f};
#pragma unroll
            for (int u = 0; u < 12; ++u) {
                int i = tid + u * 256;
                int d4 = (i - (i / 160) * 160) * 4;
                buf[u] = (rmu[u] >= 0) ? *(const float4*)(Yt + (size_t)rmu[u] * NEXT + d4) : z;
            }
#pragma unroll
            for (int u = 0; u < 12; ++u) {
                int i = tid + u * 256;
                if (i < R18 * 160) {
                    int r = i / 160, d4 = (i - r * 160) * 4;
                    *(float4*)&sv[r][d4] = buf[u];
                }
            }
        }
        __syncthreads();
        int wv = tid >> 6, lane = tid & 63;
        for (int p = wv; p < 171; p += 4) {      // wave-parallel pairs (R0 form)
            int i = 0, rem = p;
            while (rem >= R18 - i) { rem -= R18 - i; ++i; }
            int j = i + rem;
            float s = 0.f;
            for (int d = lane; d < D; d += 64) s += sv[i][d] * sv[j][d];
#pragma unroll
            for (int off = 32; off; off >>= 1) s += __shfl_xor(s, off);
            if (lane == 0) { aug[i][j] = s; aug[j][i] = s; }
        }
        for (int i2 = tid; i2 < R18 * R18; i2 += 256)   // identity half
            aug[i2 / R18][R18 + i2 % R18] = (i2 / R18 == i2 % R18) ? 1.f : 0.f;
        __syncthreads();
        int w = wv;
        if (w == 1) {                    // b0 = ||mu_c||^2, concurrent with GJ
            const float* mc = mu + (size_t)c * D;
            float s = 0.f;
            for (int d = lane; d < D; d += 64) { float v = mc[d]; s += v * v; }
#pragma unroll
            for (int off = 32; off; off >>= 1) s += __shfl_xor(s, off);
            if (lane == 0) b0[c] = s;
        }
        if (w == 0) {                    // wave 0: h/btil, diag add, lockstep GJ
            if (lane < R18) h[c * R18 + lane] = aug[lane][R18 - 1];
            if (lane == 0) btil[c] = aug[R18 - 1][R18 - 1];
            volatile float (*va)[40] = (volatile float (*)[40])aug;
            if (lane == 0) va[0][0] += 1.0f / sc[0];
            else if (lane <= KMAX) va[lane][lane] += 1.0f;
            else if (lane == R18 - 1) va[R18 - 1][R18 - 1] += sc[192 + c];
            __threadfence_block();
            for (int p = 0; p < R18; ++p) {
                float v = (lane >= p && lane < R18) ? fabsf(va[lane][p]) : -1.f;
                int bi = lane;
#pragma unroll
                for (int off = 32; off; off >>= 1) {
                    float ov = __shfl_xor(v, off);
                    int oi = __shfl_xor(bi, off);
                    if (ov > v || (ov == v && oi < bi)) { v = ov; bi = oi; }
                }
                float pv = va[bi][p];                    // broadcast read (pre-swap)
                if (lane < 2 * R18) {                    // fused swap + scale
                    float rp = va[bi][lane];
                    if (bi != p) va[bi][lane] = va[p][lane];
                    va[p][lane] = rp / pv;
                }
                __threadfence_block();
                float f  = (lane < R18) ? va[lane][p] : 0.f;
                float pr = (lane < 2 * R18) ? va[p][lane] : 0.f;
#pragma unroll
                for (int it = 0; it < 11; ++it) {
                    int e = lane + it * 64;
                    int r2 = e / 36, cc = e - r2 * 36;
                    float fr = __shfl(f, r2 < R18 ? r2 : 0);
                    float pc = __shfl(pr, cc);
                    if (e < R18 * 2 * R18 && r2 != p) va[r2][cc] -= fr * pc;
                }
                __threadfence_block();
            }
            for (int e = lane; e < R18 * R18; e += 64)
                kinv[(size_t)c * R18 * R18 + e] = va[e / R18][R18 + e % R18];
        }
    } else {
        int slot = bid - 1 - bid / 18;               // 0..1087
        if (slot < 576) {
            // ---- G GEMM: G[q][c*18+j] = x~q . v~_{c,j} (+ XCD chunk swizzle) ----
            unsigned short* Ah_s = (unsigned short*)smem;            // 4096 B each
            unsigned short* Al_s = (unsigned short*)(smem + 4096);
            unsigned short* Bh_s = (unsigned short*)(smem + 8192);
            unsigned short* Bl_s = (unsigned short*)(smem + 12288);
            int gb = xcd_chunk(slot, 576);   // 576 = 8*72: each XCD owns 4 row-panels
            int rowBase = (gb / 18) * 64, colBase = (gb % 18) * 64;
            int r = tid >> 2, e = (tid & 3) << 3;
            int gr = rowBase + r;
            int gc = colBase + r;
            int br = rowmap[gc];
            int w = tid >> 6, lane = tid & 63, q = lane >> 4, lr = lane & 15;
            int aoff = (16 * w + lr) * 32 + q * 8;
            const uint4 z4 = {0u, 0u, 0u, 0u};
            floatx4 acc[4] = {{0.f, 0.f, 0.f, 0.f}, {0.f, 0.f, 0.f, 0.f},
                              {0.f, 0.f, 0.f, 0.f}, {0.f, 0.f, 0.f, 0.f}};
            for (int kk = 0; kk < D; kk += 32) {
                uint4 vah = *(const uint4*)(Th + (size_t)gr * D + kk + e);
                uint4 val = *(const uint4*)(Tl + (size_t)gr * D + kk + e);
                uint4 vbh = (br >= 0) ? *(const uint4*)(Th + (size_t)br * D + kk + e) : z4;
                uint4 vbl = (br >= 0) ? *(const uint4*)(Tl + (size_t)br * D + kk + e) : z4;
                __syncthreads();
                *(uint4*)(Ah_s + r * 32 + e) = vah;
                *(uint4*)(Al_s + r * 32 + e) = val;
                *(uint4*)(Bh_s + r * 32 + e) = vbh;
                *(uint4*)(Bl_s + r * 32 + e) = vbl;
                __syncthreads();
                bf16x8 ah = *(const bf16x8*)(Ah_s + aoff);
                bf16x8 al = *(const bf16x8*)(Al_s + aoff);
#pragma unroll
                for (int tt = 0; tt < 4; ++tt) {
                    int boff = (16 * tt + lr) * 32 + q * 8;
                    bf16x8 bh = *(const bf16x8*)(Bh_s + boff);
                    bf16x8 bl = *(const bf16x8*)(Bl_s + boff);
                    acc[tt] = __builtin_amdgcn_mfma_f32_16x16x32_bf16(ah, bh, acc[tt], 0, 0, 0);
                    acc[tt] = __builtin_amdgcn_mfma_f32_16x16x32_bf16(ah, bl, acc[tt], 0, 0, 0);
                    acc[tt] = __builtin_amdgcn_mfma_f32_16x16x32_bf16(al, bh, acc[tt], 0, 0, 0);
                }
            }
#pragma unroll
            for (int tt = 0; tt < 4; ++tt) {
                int gc2 = colBase + 16 * tt + lr;
#pragma unroll
                for (int rg = 0; rg < 4; ++rg) {
                    int gr2 = rowBase + 16 * w + q * 4 + rg;
                    G[(size_t)gr2 * VROWS + gc2] = acc[tt][rg];
                }
            }
        } else {
            // ---- at[q] = ||Ytout_q[0:640]||^2 ----
            int gw = ((slot - 576) * 256 + tid) >> 6;
            rownorm_body(Yt, NEXT, at, gw, tid & 63);
        }
    }
}

// ---------------- epilogue ----------------------------------------------
__global__ void k_epi(const float* __restrict__ G, const float* __restrict__ Yt,
                      const float* __restrict__ at, const float* __restrict__ a0,
                      const float* __restrict__ h, const float* __restrict__ btil,
                      const float* __restrict__ b0, const float* __restrict__ kinv,
                      const float* __restrict__ sc, float* __restrict__ out) {
    __shared__ float lk[R18 * R18], lh[R18];
    __shared__ float ldn, lbt, lb0;
    int c = blockIdx.x, tid = threadIdx.x;
    for (int i = tid; i < R18 * R18; i += 256) lk[i] = kinv[(size_t)c * R18 * R18 + i];
    if (tid < R18) lh[tid] = h[c * R18 + tid];
    if (tid == 0) { ldn = sc[128 + c]; lbt = btil[c]; lb0 = b0[c]; }
    __syncthreads();
    int q = blockIdx.y * 256 + tid;
    const float* Gr = G + (size_t)q * VROWS + c * R18;
    float g[R18];
#pragma unroll
    for (int j = 0; j < R18; ++j) g[j] = Gr[j];
    float ipt = g[R18 - 1];
#pragma unroll
    for (int j = 0; j < R18; ++j) g[j] -= lh[j];
    float corr = 0.f;
#pragma unroll
    for (int i = 0; i < R18; ++i) {
        float s = 0.f;
#pragma unroll
        for (int j = 0; j < R18; ++j) s += lk[i * R18 + j] * g[j];
        corr += g[i] * s;
    }
    float ip0 = Yt[(size_t)q * NEXT + D + c];
    float tt = at[q] - 2.f * ipt + lbt;
    float t0 = a0[q] - 2.f * ip0 + lb0;
    out[(size_t)q * C + c] = -(0.7f * ldn * (tt - corr) + 0.3f * t0);
}

extern "C" void kernel_launch(void* const* d_in, const int* in_sizes, int n_in,
                              void* d_out, int out_size, void* d_ws, size_t ws_size,
                              hipStream_t stream) {
    const float* X     = (const float*)d_in[0];
    const int*   y     = (const int*)d_in[1];
    const float* Xq    = (const float*)d_in[2];
    const float* m     = (const float*)d_in[3];
    const float* kappa = (const float*)d_in[4];
    const float* nu    = (const float*)d_in[5];
    const float* tdiag = (const float*)d_in[6];
    const float* tlow  = (const float*)d_in[7];
    float* out = (float*)d_out;

    char* w = (char*)d_ws;
    auto alloc = [&](size_t bytes) {
        char* p = w;
        w += (bytes + 255) & ~(size_t)255;
        return p;
    };
    int*   cnt    = (int*)alloc(C * 4);
    int*   idx    = (int*)alloc(C * KMAX * 4);
    int*   rowmap = (int*)alloc(VROWS * 4);
    float* sc     = (float*)alloc(256 * 4);
    float* rd     = (float*)alloc(D * 4);
    float* mu     = (float*)alloc((size_t)C * D * 4);
    float* at     = (float*)alloc(Q * 4);
    float* a0     = (float*)alloc(Q * 4);
    float* h      = (float*)alloc(C * R18 * 4);
    float* btil   = (float*)alloc(C * 4);
    float* b0     = (float*)alloc(C * 4);
    float* kinv   = (float*)alloc((size_t)C * R18 * R18 * 4);
    float* Ytout  = (float*)alloc((size_t)YPAD * NEXT * 4);          // 9.0 MB
    unsigned short* Th = (unsigned short*)alloc((size_t)YPAD * D * 2); // 4.1 MB
    unsigned short* Tl = (unsigned short*)alloc((size_t)YPAD * D * 2);
    unsigned short* Bh = (unsigned short*)alloc((size_t)NEXT * D * 2); // 0.9 MB
    unsigned short* Bl = (unsigned short*)alloc((size_t)NEXT * D * 2);
    // region reused by G (all dead before the G GEMM writes):
    char* wmark = w;
    float* Linv = (float*)alloc((size_t)D * D * 4);                  // 1.6 MB
    float* Lhat = (float*)alloc((size_t)D * D * 4);                  // 1.6 MB
    unsigned short* Ah = (unsigned short*)alloc((size_t)YPAD * D * 2); // 4.1 MB
    unsigned short* Al = (unsigned short*)alloc((size_t)YPAD * D * 2);
    w = wmark;
    float* G    = (float*)alloc((size_t)Q * VROWS * 4);              // 9.4 MB

    k_setup<<<441, 256, 0, stream>>>(y, kappa, nu, tdiag, cnt, idx, sc, rd, rowmap,
                                     Ah, Al, Bh, Bl);
    k_dinv_mu<<<2753, 256, 0, stream>>>(tlow, rd, Linv, X, m, cnt, idx, sc, mu,
                                        Xq, Ah, Al, Bh, Bl, a0);
    k_lhat<<<dim3(64, 10), 256, 0, stream>>>(tlow, Linv, Lhat);
    k_linv_fill<<<32, 256, 0, stream>>>(Lhat, Linv, Bh, Bl);
    // Ytout[r][0:640] = tilde rows; [640:704] = x_r . mu_c; epilogue packs Th/Tl
    k_mfma_nt<<<dim3(NEXT / 64, YPAD / 64), 256, 0, stream>>>(
        Ah, Al, Bh, Bl, Ytout, YPAD, NEXT, NEXT, Th, Tl);
    // gram (spread, 1/CU) + G GEMM + at, one dispatch
    k_gv<<<1152, 256, 0, stream>>>(Th, Tl, rowmap, G, Ytout, mu, sc, at,
                                   h, btil, b0, kinv);
    k_epi<<<dim3(C, Q / 256), 256, 0, stream>>>(G, Ytout, at, a0, h, btil, b0, kinv, sc, out);
}

// Round 12
// 217.309 us; speedup vs baseline: 1.1980x; 1.1980x over previous
//
#include <hip/hip_runtime.h>
#include <hip/hip_bf16.h>

// MetaQDA MAP. D=640, C=64, N=1024, Q=2048, REG=0.3.
// sigma_c*denom = L L^T + U_c J_c U_c^T (rank 18) => Woodbury.
// Round 17: R15 (L2 gram) and R16 (gram spread + wave-dots) both regressed;
// R14 = 214us stands. Conflicts proved NOT gram-dot-sourced (R16: unchanged
// 1.9M with stride-1 dots) and not the limiter (R12). One lever left with
// measured precedent (learn_hip m92->m93: 64->128 tile = +51% at the same
// 2-barrier structure): both GEMMs 64x64 -> 128x64 tiles (acc[2][4]/wave).
// Barriers per output halve; MFMA:ds_read 12:10 -> 24:12. K-order and
// per-element MFMA chain unchanged => bitwise-identical (absmax 24576).
// Everything else byte-identical to R14.
// Gram stays fp32 (round-6 post-mortem: bf16 Gram -> absmax 1.8e7).

#define D 640
#define C 64
#define NSUP 1024
#define Q 2048
#define KMAX 16
#define R18 18           // Woodbury rank: 1 (m) + 16 (x) + 1 (mu)
#define VROWS (C * R18)  // 1152
#define YROWS 3137       // 2048 Xq + 1024 X + 1 m + 64 mu
#define YPAD 3200
#define NEXT 704         // 640 tilde cols + 64 ip0 cols

typedef __attribute__((ext_vector_type(8))) short bf16x8;
typedef __attribute__((ext_vector_type(4))) float floatx4;

__device__ __forceinline__ unsigned short f2bf(float x) {
    unsigned int u = __float_as_uint(x);
    unsigned int r = u + 0x7FFFu + ((u >> 16) & 1u);
    return (unsigned short)(r >> 16);
}

__device__ __forceinline__ void pack4(const float* vv, unsigned short* hp, unsigned short* lp) {
#pragma unroll
    for (int i = 0; i < 4; ++i) {
        unsigned short hb = f2bf(vv[i]);
        float hf = __uint_as_float((unsigned int)hb << 16);
        hp[i] = hb;
        lp[i] = f2bf(vv[i] - hf);
    }
}

__device__ __forceinline__ void rownorm_body(const float* __restrict__ A, int ld,
                                             float* __restrict__ out, int gw, int lane) {
    const float* row = A + (size_t)gw * ld;
    float s = 0.f;
    for (int d = lane; d < D; d += 64) { float v = row[d]; s += v * v; }
#pragma unroll
    for (int off = 32; off; off >>= 1) s += __shfl_xor(s, off);
    if (lane == 0) out[gw] = s;
}

// bijective chunked XCD swizzle (m204): round-robin pos -> contiguous chunk
__device__ __forceinline__ int xcd_chunk(int orig, int nwg) {
    int q = nwg >> 3, r = nwg & 7;
    int xcd = orig & 7, pos = orig >> 3;
    return (xcd < r) ? xcd * (q + 1) + pos
                     : r * (q + 1) + (xcd - r) * q + pos;
}

// ---------------- setup (block 0) + zero Bh/Bl[0:640] & Ah/Al pad rows ---
#define BZCH (640 * 640 / 8)          // 51200 16B-chunks per B array
#define AZCH (63 * 640 / 8)           // 5040 16B-chunks per A pad region
__global__ void k_setup(const int* __restrict__ y, const float* __restrict__ kappa,
                        const float* __restrict__ nu, const float* __restrict__ diag,
                        int* __restrict__ cnt, int* __restrict__ idx,
                        float* __restrict__ sc, float* __restrict__ rd,
                        int* __restrict__ rowmap,
                        unsigned short* __restrict__ Ah, unsigned short* __restrict__ Al,
                        unsigned short* __restrict__ Bh, unsigned short* __restrict__ Bl) {
    int tid = threadIdx.x;
    if (blockIdx.x > 0) {
        int id = (blockIdx.x - 1) * 256 + tid;
        const uint4 z = {0u, 0u, 0u, 0u};
        if (id < BZCH) ((uint4*)Bh)[id] = z;
        else if (id < 2 * BZCH) ((uint4*)Bl)[id - BZCH] = z;
        else if (id < 2 * BZCH + AZCH) ((uint4*)(Ah + (size_t)YROWS * D))[id - 2 * BZCH] = z;
        else if (id < 2 * BZCH + 2 * AZCH) ((uint4*)(Al + (size_t)YROWS * D))[id - 2 * BZCH - AZCH] = z;
        return;
    }
    __shared__ int lc[C];
    if (tid < C) lc[tid] = 0;
    __syncthreads();
    for (int n = tid; n < NSUP; n += 256) {
        int c = y[n];
        int k = atomicAdd(&lc[c], 1);
        if (k < KMAX) idx[c * KMAX + k] = n;
    }
    __syncthreads();
    for (int d = tid; d < D; d += 256) rd[d] = 1.0f / fabsf(diag[d]);
    if (tid < C) {
        int n = lc[tid]; if (n > KMAX) n = KMAX;
        cnt[tid] = n;
        float kap = fabsf(kappa[0]) + 1e-6f;
        float nuv = fmaxf(nu[0], (float)(D - 1) + 1e-6f);
        float Ncf = (float)n;
        sc[64 + tid]  = Ncf / (kap + Ncf);            // w_c
        sc[128 + tid] = nuv + Ncf + (float)(D + 2);   // denom_c
        sc[192 + tid] = -1.0f / (kap + Ncf);          // J^{-1} last diag
        if (tid == 0) { sc[0] = kap; sc[1] = nuv; }
    }
    __syncthreads();
    for (int i = tid; i < VROWS; i += 256) {
        int c = i / R18, j = i - c * R18;
        int nc = lc[c] < KMAX ? lc[c] : KMAX;
        int rm;
        if (j == 0) rm = Q + NSUP;                       // m~
        else if (j <= KMAX) rm = (j - 1 < nc) ? Q + idx[c * KMAX + j - 1] : -1;
        else rm = Q + NSUP + 1 + c;                      // mu~
        rowmap[i] = rm;
    }
}

// ---------------- fused: dinv + mu + pack(Xq,X,m) + a0 -------------------
__global__ __launch_bounds__(256) void k_dinv_mu(
        const float* __restrict__ tlow, const float* __restrict__ rd,
        float* __restrict__ Linv,
        const float* __restrict__ X, const float* __restrict__ m,
        const int* __restrict__ cnt, const int* __restrict__ idx,
        const float* __restrict__ sc, float* __restrict__ mu,
        const float* __restrict__ Xq,
        unsigned short* __restrict__ Ah, unsigned short* __restrict__ Al,
        unsigned short* __restrict__ Bh, unsigned short* __restrict__ Bl,
        float* __restrict__ a0) {
    __shared__ float Lst[128 * 128];
    int tid = threadIdx.x;
    int bid = blockIdx.x;
    if (bid < 160) {
        int b = bid >> 5;
        int j = ((bid & 31) << 2) + (tid >> 6);
        int lane = tid & 63;
        int bB = b * 128;
        {
            float4 tv[16];
            float rv[16];
#pragma unroll
            for (int u = 0; u < 16; ++u) {
                int e = tid + u * 256;              // e = r*32 + c4/4, covers 128x32
                int c4 = (e & 31) * 4, r = e >> 5;
                tv[u] = *(const float4*)(tlow + (size_t)(bB + r) * D + bB + c4);
                rv[u] = rd[bB + r];
            }
#pragma unroll
            for (int u = 0; u < 16; ++u) {
                int e = tid + u * 256;
                int c4 = (e & 31) * 4, r = e >> 5;
                float vv[4] = {tv[u].x, tv[u].y, tv[u].z, tv[u].w};
#pragma unroll
                for (int t = 0; t < 4; ++t) {
                    int c = c4 + t;
                    float v;
                    if (r == c) v = 1.0f;
                    else if (r > c) v = rv[u] * vv[t];
                    else v = 0.f;
                    Lst[c * 128 + (r ^ (c & 63))] = v;
                }
            }
        }
        __syncthreads();
        float rd0 = rd[bB + lane], rd1 = rd[bB + 64 + lane];
        float acc0 = 0.f, acc1 = 0.f, zz0 = 0.f, zz1 = 0.f;
        for (int i = j; i < 128; ++i) {
            int ri = i >> 6, il = i & 63;
            float av = (ri == 0) ? acc0 : acc1;
            float ai = __shfl(av, il);
            float zi = (i == j) ? __shfl((ri == 0) ? rd0 : rd1, il) : -ai;
            int sw = i & 63;
            float l0 = Lst[i * 128 + (lane ^ sw)];
            float l1 = Lst[i * 128 + 64 + (lane ^ sw)];
            if (lane > i) acc0 += l0 * zi;
            if (64 + lane > i) acc1 += l1 * zi;
            if (lane == i) zz0 = zi;
            if (64 + lane == i) zz1 = zi;
        }
        Linv[(size_t)(bB + lane) * D + bB + j] = zz0;
        Linv[(size_t)(bB + 64 + lane) * D + bB + j] = zz1;
        unsigned short h0 = f2bf(zz0);
        float hf0 = __uint_as_float((unsigned int)h0 << 16);
        Bh[(size_t)(bB + lane) * D + bB + j] = h0;
        Bl[(size_t)(bB + lane) * D + bB + j] = f2bf(zz0 - hf0);
        unsigned short h1 = f2bf(zz1);
        float hf1 = __uint_as_float((unsigned int)h1 << 16);
        Bh[(size_t)(bB + 64 + lane) * D + bB + j] = h1;
        Bl[(size_t)(bB + 64 + lane) * D + bB + j] = f2bf(zz1 - hf1);
    } else if (bid < 320) {
        int u = (bid - 160) * 2 + (tid >> 7);     // 0..319
        int c = u / 5, by = u - c * 5;
        int d = by * 128 + (tid & 127);
        int n = cnt[c];
        float s = 0.f;
        for (int k = 0; k < n; ++k) s += X[(size_t)idx[c * KMAX + k] * D + d];
        float w = sc[64 + c];
        float mean = (n > 0) ? s / (float)n : 0.f;
        float val = (1.f - w) * m[d] + w * mean;
        mu[(size_t)c * D + d] = val;
        unsigned short hb = f2bf(val);
        float hf = __uint_as_float((unsigned int)hb << 16);
        unsigned short lb = f2bf(val - hf);
        Ah[(size_t)(Q + NSUP + 1 + c) * D + d] = hb;   // A row 3073+c
        Al[(size_t)(Q + NSUP + 1 + c) * D + d] = lb;
        Bh[(size_t)(D + c) * D + d] = hb;              // B row 640+c
        Bl[(size_t)(D + c) * D + d] = lb;
    } else if (bid < 2240) {
        int gid = (bid - 320) * 256 + tid;             // rows 0..3071
        int row = gid / 160, c = (gid - row * 160) * 4;
        float4 v = (row < Q) ? *(const float4*)(Xq + (size_t)row * D + c)
                             : *(const float4*)(X + (size_t)(row - Q) * D + c);
        float vv[4] = {v.x, v.y, v.z, v.w};
        ushort4 h, l;
        pack4(vv, (unsigned short*)&h, (unsigned short*)&l);
        *(ushort4*)(Ah + (size_t)row * D + c) = h;
        *(ushort4*)(Al + (size_t)row * D + c) = l;
    } else if (bid == 2240) {
        if (tid < 160) {
            int c = tid * 4;
            float4 v = *(const float4*)(m + c);
            float vv[4] = {v.x, v.y, v.z, v.w};
            ushort4 h, l;
            pack4(vv, (unsigned short*)&h, (unsigned short*)&l);
            *(ushort4*)(Ah + (size_t)(Q + NSUP) * D + c) = h;   // row 3072
            *(ushort4*)(Al + (size_t)(Q + NSUP) * D + c) = l;
        }
    } else {
        int gw = ((bid - 2241) * 256 + tid) >> 6;      // 0..2047
        rownorm_body(Xq, D, a0, gw, tid & 63);
    }
}

// ---------------- Lhat_ik = Dinv_i * L_ik (strict-lower blocks) ----------
__global__ void k_lhat(const float* __restrict__ tlow, const float* __restrict__ Linv,
                       float* __restrict__ Lhat) {
    const int bi_tab[10] = {1, 2, 2, 3, 3, 3, 4, 4, 4, 4};
    const int bk_tab[10] = {0, 0, 1, 0, 1, 2, 0, 1, 2, 3};
    int p = blockIdx.y;
    int bi = bi_tab[p], bk = bk_tab[p];
    int tid = threadIdx.x;
    int c = tid & 127;
    int r = (blockIdx.x << 1) + (tid >> 7);
    const float* drow = Linv + (size_t)(bi * 128 + r) * D + bi * 128;
    const float* lcol = tlow + (size_t)(bi * 128) * D + bk * 128 + c;
    float s = 0.f;
#pragma unroll 4
    for (int t = 0; t < 128; ++t) s += drow[t] * lcol[(size_t)t * D];
    Lhat[(size_t)(bi * 128 + r) * D + bk * 128 + c] = s;
}

// ---------------- Linv off-diag: right-looking strip recurrence ----------
template<int B>
__device__ __forceinline__ void linv_chain(const float* __restrict__ Lhat,
                                           float* __restrict__ Linv,
                                           unsigned short* __restrict__ Bh,
                                           unsigned short* __restrict__ Bl,
                                           float S[4][128][20],
                                           int cB, int tid) {
    const int ty = tid >> 2, tx = tid & 3;   // rows {2ty,2ty+1}, cols 4tx..4tx+3
    const int r0 = 2 * ty;
    float acc[4 - B][2][4];
#pragma unroll
    for (int a = 0; a < 4 - B; ++a)
#pragma unroll
        for (int rr = 0; rr < 2; ++rr)
#pragma unroll
            for (int cc = 0; cc < 4; ++cc) acc[a][rr][cc] = 0.f;
#pragma unroll
    for (int js = 0; js < 4 - B; ++js) {     // contraction block j = B + js
        const int j = B + js;
        for (int k0 = 0; k0 < 128; k0 += 8) {
            float svf[8][4];
#pragma unroll
            for (int u = 0; u < 8; ++u) {
                float4 s4 = *(const float4*)&S[js][k0 + u][tx * 4];
                svf[u][0] = s4.x; svf[u][1] = s4.y; svf[u][2] = s4.z; svf[u][3] = s4.w;
            }
#pragma unroll
            for (int a = js; a < 4 - B; ++a) {   // output block i = B + 1 + a
                const int i = B + 1 + a;
                const float* p0 = Lhat + (size_t)(i * 128 + r0) * D + j * 128 + k0;
                const float* p1 = p0 + D;
                float4 a00 = *(const float4*)(p0);
                float4 a01 = *(const float4*)(p0 + 4);
                float4 a10 = *(const float4*)(p1);
                float4 a11 = *(const float4*)(p1 + 4);
                float ar0[8] = {a00.x, a00.y, a00.z, a00.w, a01.x, a01.y, a01.z, a01.w};
                float ar1[8] = {a10.x, a10.y, a10.z, a10.w, a11.x, a11.y, a11.z, a11.w};
#pragma unroll
                for (int u = 0; u < 8; ++u) {
#pragma unroll
                    for (int cc = 0; cc < 4; ++cc) {
                        acc[a][0][cc] += ar0[u] * svf[u][cc];
                        acc[a][1][cc] += ar1[u] * svf[u][cc];
                    }
                }
            }
        }
        {
            const int i = j + 1;
#pragma unroll
            for (int rr = 0; rr < 2; ++rr) {
                const int r = r0 + rr;
                float vv[4];
#pragma unroll
                for (int cc = 0; cc < 4; ++cc) vv[cc] = -acc[js][rr][cc];
                float4 v = {vv[0], vv[1], vv[2], vv[3]};
                if (js + 1 < 4 - B) *(float4*)&S[js + 1][r][tx * 4] = v;
                *(float4*)(Linv + (size_t)(i * 128 + r) * D + cB + tx * 4) = v;
                ushort4 hh, ll;
                pack4(vv, (unsigned short*)&hh, (unsigned short*)&ll);
                *(ushort4*)(Bh + (size_t)(i * 128 + r) * D + cB + tx * 4) = hh;
                *(ushort4*)(Bl + (size_t)(i * 128 + r) * D + cB + tx * 4) = ll;
            }
        }
        if (js + 1 < 4 - B) __syncthreads();
    }
}

__global__ __launch_bounds__(256) void k_linv_fill(const float* __restrict__ Lhat,
                                                   float* __restrict__ Linv,
                                                   unsigned short* __restrict__ Bh,
                                                   unsigned short* __restrict__ Bl) {
    __shared__ __align__(16) float S[4][128][20];   // 40 KB
    int tid = threadIdx.x;
    int b = blockIdx.x >> 3, strip = blockIdx.x & 7;
    int bB = b * 128, cB = bB + strip * 16;
    {   // load S[0] strip from the Dinv block already in Linv
        int r = tid >> 1, c0 = (tid & 1) * 8;
        const float* src = Linv + (size_t)(bB + r) * D + cB + c0;
        *(float4*)&S[0][r][c0]     = *(const float4*)(src);
        *(float4*)&S[0][r][c0 + 4] = *(const float4*)(src + 4);
    }
    __syncthreads();
    if (b == 0)      linv_chain<0>(Lhat, Linv, Bh, Bl, S, cB, tid);
    else if (b == 1) linv_chain<1>(Lhat, Linv, Bh, Bl, S, cB, tid);
    else if (b == 2) linv_chain<2>(Lhat, Linv, Bh, Bl, S, cB, tid);
    else             linv_chain<3>(Lhat, Linv, Bh, Bl, S, cB, tid);
}

// ---------------- split-bf16 MFMA NT GEMM, 128x64 tile -------------------
// acc[2][4] per wave (2 row-frags x 4 col-frags); K-order and per-element
// MFMA chain identical to the 64x64 version => bitwise-identical output.
// Chunked XCD swizzle (T1). If Th != nullptr, epilogue packs cols < 640.
__global__ __launch_bounds__(256) void k_mfma_nt(
        const unsigned short* __restrict__ Ah, const unsigned short* __restrict__ Al,
        const unsigned short* __restrict__ Bh, const unsigned short* __restrict__ Bl,
        float* __restrict__ Out, int M, int N, int ldo,
        unsigned short* __restrict__ Th, unsigned short* __restrict__ Tl) {
    __shared__ unsigned short Ah_s[128 * 32], Al_s[128 * 32];   // 8192 B each
    __shared__ unsigned short Bh_s[64 * 32],  Bl_s[64 * 32];    // 4096 B each
    int tid = threadIdx.x;
    int nbx = gridDim.x, nwg = nbx * gridDim.y;
    int orig = blockIdx.y * nbx + blockIdx.x;
    int wgid = xcd_chunk(orig, nwg);                 // contiguous chunk per XCD
    int rowBase = (wgid / nbx) * 128, colBase = (wgid % nbx) * 64;
    int r = tid >> 2, e = (tid & 3) << 3;            // r 0..63, e 0/8/16/24
    int gra0 = rowBase + r, gra1 = rowBase + 64 + r;
    int gcb = colBase + r;
    bool a0ok = (gra0 < M), a1ok = (gra1 < M), bok = (gcb < N);
    int w = tid >> 6, lane = tid & 63, q = lane >> 4, lr = lane & 15;
    const uint4 z4 = {0u, 0u, 0u, 0u};
    floatx4 acc[2][4];
#pragma unroll
    for (int ar = 0; ar < 2; ++ar)
#pragma unroll
        for (int tt = 0; tt < 4; ++tt) acc[ar][tt] = (floatx4){0.f, 0.f, 0.f, 0.f};
    for (int kk = 0; kk < D; kk += 32) {
        uint4 va0h = a0ok ? *(const uint4*)(Ah + (size_t)gra0 * D + kk + e) : z4;
        uint4 va0l = a0ok ? *(const uint4*)(Al + (size_t)gra0 * D + kk + e) : z4;
        uint4 va1h = a1ok ? *(const uint4*)(Ah + (size_t)gra1 * D + kk + e) : z4;
        uint4 va1l = a1ok ? *(const uint4*)(Al + (size_t)gra1 * D + kk + e) : z4;
        uint4 vbh = bok ? *(const uint4*)(Bh + (size_t)gcb * D + kk + e) : z4;
        uint4 vbl = bok ? *(const uint4*)(Bl + (size_t)gcb * D + kk + e) : z4;
        __syncthreads();
        *(uint4*)(Ah_s + r * 32 + e)          = va0h;
        *(uint4*)(Al_s + r * 32 + e)          = va0l;
        *(uint4*)(Ah_s + (64 + r) * 32 + e)   = va1h;
        *(uint4*)(Al_s + (64 + r) * 32 + e)   = va1l;
        *(uint4*)(Bh_s + r * 32 + e)          = vbh;
        *(uint4*)(Bl_s + r * 32 + e)          = vbl;
        __syncthreads();
#pragma unroll
        for (int ar = 0; ar < 2; ++ar) {
            int aoff = (32 * w + 16 * ar + lr) * 32 + q * 8;
            bf16x8 ah = *(const bf16x8*)(Ah_s + aoff);
            bf16x8 al = *(const bf16x8*)(Al_s + aoff);
#pragma unroll
            for (int tt = 0; tt < 4; ++tt) {
                int boff = (16 * tt + lr) * 32 + q * 8;
                bf16x8 bh = *(const bf16x8*)(Bh_s + boff);
                bf16x8 bl = *(const bf16x8*)(Bl_s + boff);
                acc[ar][tt] = __builtin_amdgcn_mfma_f32_16x16x32_bf16(ah, bh, acc[ar][tt], 0, 0, 0);
                acc[ar][tt] = __builtin_amdgcn_mfma_f32_16x16x32_bf16(ah, bl, acc[ar][tt], 0, 0, 0);
                acc[ar][tt] = __builtin_amdgcn_mfma_f32_16x16x32_bf16(al, bh, acc[ar][tt], 0, 0, 0);
            }
        }
    }
#pragma unroll
    for (int ar = 0; ar < 2; ++ar) {
#pragma unroll
        for (int tt = 0; tt < 4; ++tt) {
            int gc2 = colBase + 16 * tt + lr;
#pragma unroll
            for (int rg = 0; rg < 4; ++rg) {
                int gr2 = rowBase + 32 * w + 16 * ar + q * 4 + rg;
                if (gr2 < M && gc2 < N) {
                    float v = acc[ar][tt][rg];
                    Out[(size_t)gr2 * ldo + gc2] = v;
                    if (Th && gc2 < D) {
                        unsigned short hb = f2bf(v);
                        float hf = __uint_as_float((unsigned int)hb << 16);
                        Th[(size_t)gr2 * D + gc2] = hb;
                        Tl[(size_t)gr2 * D + gc2] = f2bf(v - hf);
                    }
                }
            }
        }
    }
}

// ---------------- fused: gram_inv (64) + G GEMM (288) + at (512) ---------
// Gram = R14 form (LDS-staged, thread-per-pair, 24576-stable). G GEMM =
// 128x64 tile (16 row-panels x 18 col-tiles), XCD-chunked.
__global__ __launch_bounds__(256) void k_gv(
        const unsigned short* __restrict__ Th, const unsigned short* __restrict__ Tl,
        const int* __restrict__ rowmap, float* __restrict__ G,
        const float* __restrict__ Yt, const float* __restrict__ mu,
        const float* __restrict__ sc, float* __restrict__ at,
        float* __restrict__ h, float* __restrict__ btil,
        float* __restrict__ b0, float* __restrict__ kinv) {
    __shared__ __align__(16) char smem[49344];
    int bid = blockIdx.x, tid = threadIdx.x;
    if (bid < 64) {
        // ---- per-class fp32 Gram (LDS-staged) + 1-wave GJ ----
        float (*sv)[644] = (float(*)[644])smem;                 // 46368 B
        float (*aug)[40] = (float(*)[40])(smem + 46368);        //  2880 B
        int* rmv = (int*)(smem + 46368 + 2880);                 //    72 B
        int c = bid;
        if (tid < R18) rmv[tid] = rowmap[c * R18 + tid];
        __syncthreads();
        {   // batched staging: 12 independent float4 loads per thread
            int rmu[12];
#pragma unroll
            for (int u = 0; u < 12; ++u) {
                int i = tid + u * 256;
                int r = i / 160;
                rmu[u] = (i < R18 * 160) ? rmv[r] : -1;
            }
            float4 buf[12];
            const float4 z = {0.f, 0.f, 0.f, 0.f};
#pragma unroll
            for (int u = 0; u < 12; ++u) {
                int i = tid + u * 256;
                int d4 = (i - (i / 160) * 160) * 4;
                buf[u] = (rmu[u] >= 0) ? *(const float4*)(Yt + (size_t)rmu[u] * NEXT + d4) : z;
            }
#pragma unroll
            for (int u = 0; u < 12; ++u) {
                int i = tid + u * 256;
                if (i < R18 * 160) {
                    int r = i / 160, d4 = (i - r * 160) * 4;
                    *(float4*)&sv[r][d4] = buf[u];
                }
            }
        }
        __syncthreads();
        if (tid < 171) {                 // one thread per (i<=j) pair
            int i = 0, rem = tid;
            while (rem >= R18 - i) { rem -= R18 - i; ++i; }
            int j = i + rem;
            const float* ri = sv[i];
            const float* rj = sv[j];
            float s0 = 0.f, s1 = 0.f, s2 = 0.f, s3 = 0.f;
#pragma unroll 4
            for (int d = 0; d < D; d += 4) {
                float4 a = *(const float4*)(ri + d);
                float4 bb = *(const float4*)(rj + d);
                s0 += a.x * bb.x; s1 += a.y * bb.y;
                s2 += a.z * bb.z; s3 += a.w * bb.w;
            }
            float s = (s0 + s1) + (s2 + s3);
            aug[i][j] = s;
            if (i != j) aug[j][i] = s;
        }
        for (int i2 = tid; i2 < R18 * R18; i2 += 256)   // identity half
            aug[i2 / R18][R18 + i2 % R18] = (i2 / R18 == i2 % R18) ? 1.f : 0.f;
        __syncthreads();
        int w = tid >> 6, lane = tid & 63;
        if (w == 1) {                    // b0 = ||mu_c||^2, concurrent with GJ
            const float* mc = mu + (size_t)c * D;
            float s = 0.f;
            for (int d = lane; d < D; d += 64) { float v = mc[d]; s += v * v; }
#pragma unroll
            for (int off = 32; off; off >>= 1) s += __shfl_xor(s, off);
            if (lane == 0) b0[c] = s;
        }
        if (w == 0) {                    // wave 0: h/btil, diag add, lockstep GJ
            if (lane < R18) h[c * R18 + lane] = aug[lane][R18 - 1];
            if (lane == 0) btil[c] = aug[R18 - 1][R18 - 1];
            volatile float (*va)[40] = (volatile float (*)[40])aug;
            if (lane == 0) va[0][0] += 1.0f / sc[0];
            else if (lane <= KMAX) va[lane][lane] += 1.0f;
            else if (lane == R18 - 1) va[R18 - 1][R18 - 1] += sc[192 + c];
            __threadfence_block();
            for (int p = 0; p < R18; ++p) {
                float v = (lane >= p && lane < R18) ? fabsf(va[lane][p]) : -1.f;
                int bi = lane;
#pragma unroll
                for (int off = 32; off; off >>= 1) {
                    float ov = __shfl_xor(v, off);
                    int oi = __shfl_xor(bi, off);
                    if (ov > v || (ov == v && oi < bi)) { v = ov; bi = oi; }
                }
                float pv = va[bi][p];                    // broadcast read (pre-swap)
                if (lane < 2 * R18) {                    // fused swap + scale
                    float rp = va[bi][lane];
                    if (bi != p) va[bi][lane] = va[p][lane];
                    va[p][lane] = rp / pv;
                }
                __threadfence_block();
                float f  = (lane < R18) ? va[lane][p] : 0.f;
                float pr = (lane < 2 * R18) ? va[p][lane] : 0.f;
#pragma unroll
                for (int it = 0; it < 11; ++it) {
                    int e = lane + it * 64;
                    int r2 = e / 36, cc = e - r2 * 36;
                    float fr = __shfl(f, r2 < R18 ? r2 : 0);
                    float pc = __shfl(pr, cc);
                    if (e < R18 * 2 * R18 && r2 != p) va[r2][cc] -= fr * pc;
                }
                __threadfence_block();
            }
            for (int e = lane; e < R18 * R18; e += 64)
                kinv[(size_t)c * R18 * R18 + e] = va[e / R18][R18 + e % R18];
        }
    } else if (bid < 64 + 288) {
        // ---- G GEMM: 128x64 tile, G[q][c*18+j] = x~q . v~_{c,j} ----
        unsigned short* Ah_s = (unsigned short*)smem;            // 8192 B
        unsigned short* Al_s = (unsigned short*)(smem + 8192);   // 8192 B
        unsigned short* Bh_s = (unsigned short*)(smem + 16384);  // 4096 B
        unsigned short* Bl_s = (unsigned short*)(smem + 20480);  // 4096 B
        int gb0 = bid - 64;
        int gb = xcd_chunk(gb0, 288);    // 288 = 8*36: contiguous chunk per XCD
        int rowBase = (gb / 18) * 128, colBase = (gb % 18) * 64;
        int r = tid >> 2, e = (tid & 3) << 3;
        int gra0 = rowBase + r, gra1 = rowBase + 64 + r;
        int br = rowmap[colBase + r];
        int w = tid >> 6, lane = tid & 63, q = lane >> 4, lr = lane & 15;
        const uint4 z4 = {0u, 0u, 0u, 0u};
        floatx4 acc[2][4];
#pragma unroll
        for (int ar = 0; ar < 2; ++ar)
#pragma unroll
            for (int tt = 0; tt < 4; ++tt) acc[ar][tt] = (floatx4){0.f, 0.f, 0.f, 0.f};
        for (int kk = 0; kk < D; kk += 32) {
            uint4 va0h = *(const uint4*)(Th + (size_t)gra0 * D + kk + e);
            uint4 va0l = *(const uint4*)(Tl + (size_t)gra0 * D + kk + e);
            uint4 va1h = *(const uint4*)(Th + (size_t)gra1 * D + kk + e);
            uint4 va1l = *(const uint4*)(Tl + (size_t)gra1 * D + kk + e);
            uint4 vbh = (br >= 0) ? *(const uint4*)(Th + (size_t)br * D + kk + e) : z4;
            uint4 vbl = (br >= 0) ? *(const uint4*)(Tl + (size_t)br * D + kk + e) : z4;
            __syncthreads();
            *(uint4*)(Ah_s + r * 32 + e)        = va0h;
            *(uint4*)(Al_s + r * 32 + e)        = va0l;
            *(uint4*)(Ah_s + (64 + r) * 32 + e) = va1h;
            *(uint4*)(Al_s + (64 + r) * 32 + e) = va1l;
            *(uint4*)(Bh_s + r * 32 + e)        = vbh;
            *(uint4*)(Bl_s + r * 32 + e)        = vbl;
            __syncthreads();
#pragma unroll
            for (int ar = 0; ar < 2; ++ar) {
                int aoff = (32 * w + 16 * ar + lr) * 32 + q * 8;
                bf16x8 ah = *(const bf16x8*)(Ah_s + aoff);
                bf16x8 al = *(const bf16x8*)(Al_s + aoff);
#pragma unroll
                for (int tt = 0; tt < 4; ++tt) {
                    int boff = (16 * tt + lr) * 32 + q * 8;
                    bf16x8 bh = *(const bf16x8*)(Bh_s + boff);
                    bf16x8 bl = *(const bf16x8*)(Bl_s + boff);
                    acc[ar][tt] = __builtin_amdgcn_mfma_f32_16x16x32_bf16(ah, bh, acc[ar][tt], 0, 0, 0);
                    acc[ar][tt] = __builtin_amdgcn_mfma_f32_16x16x32_bf16(ah, bl, acc[ar][tt], 0, 0, 0);
                    acc[ar][tt] = __builtin_amdgcn_mfma_f32_16x16x32_bf16(al, bh, acc[ar][tt], 0, 0, 0);
                }
            }
        }
#pragma unroll
        for (int ar = 0; ar < 2; ++ar) {
#pragma unroll
            for (int tt = 0; tt < 4; ++tt) {
                int gc2 = colBase + 16 * tt + lr;
#pragma unroll
                for (int rg = 0; rg < 4; ++rg) {
                    int gr2 = rowBase + 32 * w + 16 * ar + q * 4 + rg;
                    G[(size_t)gr2 * VROWS + gc2] = acc[ar][tt][rg];
                }
            }
        }
    } else {
        // ---- at[q] = ||Ytout_q[0:640]||^2 ----
        int gw = ((bid - (64 + 288)) * 256 + tid) >> 6;
        rownorm_body(Yt, NEXT, at, gw, tid & 63);
    }
}

// ---------------- epilogue ----------------------------------------------
__global__ void k_epi(const float* __restrict__ G, const float* __restrict__ Yt,
                      const float* __restrict__ at, const float* __restrict__ a0,
                      const float* __restrict__ h, const float* __restrict__ btil,
                      const float* __restrict__ b0, const float* __restrict__ kinv,
                      const float* __restrict__ sc, float* __restrict__ out) {
    __shared__ float lk[R18 * R18], lh[R18];
    __shared__ float ldn, lbt, lb0;
    int c = blockIdx.x, tid = threadIdx.x;
    for (int i = tid; i < R18 * R18; i += 256) lk[i] = kinv[(size_t)c * R18 * R18 + i];
    if (tid < R18) lh[tid] = h[c * R18 + tid];
    if (tid == 0) { ldn = sc[128 + c]; lbt = btil[c]; lb0 = b0[c]; }
    __syncthreads();
    int q = blockIdx.y * 256 + tid;
    const float* Gr = G + (size_t)q * VROWS + c * R18;
    float g[R18];
#pragma unroll
    for (int j = 0; j < R18; ++j) g[j] = Gr[j];
    float ipt = g[R18 - 1];
#pragma unroll
    for (int j = 0; j < R18; ++j) g[j] -= lh[j];
    float corr = 0.f;
#pragma unroll
    for (int i = 0; i < R18; ++i) {
        float s = 0.f;
#pragma unroll
        for (int j = 0; j < R18; ++j) s += lk[i * R18 + j] * g[j];
        corr += g[i] * s;
    }
    float ip0 = Yt[(size_t)q * NEXT + D + c];
    float tt = at[q] - 2.f * ipt + lbt;
    float t0 = a0[q] - 2.f * ip0 + lb0;
    out[(size_t)q * C + c] = -(0.7f * ldn * (tt - corr) + 0.3f * t0);
}

extern "C" void kernel_launch(void* const* d_in, const int* in_sizes, int n_in,
                              void* d_out, int out_size, void* d_ws, size_t ws_size,
                              hipStream_t stream) {
    const float* X     = (const float*)d_in[0];
    const int*   y     = (const int*)d_in[1];
    const float* Xq    = (const float*)d_in[2];
    const float* m     = (const float*)d_in[3];
    const float* kappa = (const float*)d_in[4];
    const float* nu    = (const float*)d_in[5];
    const float* tdiag = (const float*)d_in[6];
    const float* tlow  = (const float*)d_in[7];
    float* out = (float*)d_out;

    char* w = (char*)d_ws;
    auto alloc = [&](size_t bytes) {
        char* p = w;
        w += (bytes + 255) & ~(size_t)255;
        return p;
    };
    int*   cnt    = (int*)alloc(C * 4);
    int*   idx    = (int*)alloc(C * KMAX * 4);
    int*   rowmap = (int*)alloc(VROWS * 4);
    float* sc     = (float*)alloc(256 * 4);
    float* rd     = (float*)alloc(D * 4);
    float* mu     = (float*)alloc((size_t)C * D * 4);
    float* at     = (float*)alloc(Q * 4);
    float* a0     = (float*)alloc(Q * 4);
    float* h      = (float*)alloc(C * R18 * 4);
    float* btil   = (float*)alloc(C * 4);
    float* b0     = (float*)alloc(C * 4);
    float* kinv   = (float*)alloc((size_t)C * R18 * R18 * 4);
    float* Ytout  = (float*)alloc((size_t)YPAD * NEXT * 4);          // 9.0 MB
    unsigned short* Th = (unsigned short*)alloc((size_t)YPAD * D * 2); // 4.1 MB
    unsigned short* Tl = (unsigned short*)alloc((size_t)YPAD * D * 2);
    unsigned short* Bh = (unsigned short*)alloc((size_t)NEXT * D * 2); // 0.9 MB
    unsigned short* Bl = (unsigned short*)alloc((size_t)NEXT * D * 2);
    // region reused by G (all dead before the G GEMM writes):
    char* wmark = w;
    float* Linv = (float*)alloc((size_t)D * D * 4);                  // 1.6 MB
    float* Lhat = (float*)alloc((size_t)D * D * 4);                  // 1.6 MB
    unsigned short* Ah = (unsigned short*)alloc((size_t)YPAD * D * 2); // 4.1 MB
    unsigned short* Al = (unsigned short*)alloc((size_t)YPAD * D * 2);
    w = wmark;
    float* G    = (float*)alloc((size_t)Q * VROWS * 4);              // 9.4 MB

    k_setup<<<441, 256, 0, stream>>>(y, kappa, nu, tdiag, cnt, idx, sc, rd, rowmap,
                                     Ah, Al, Bh, Bl);
    k_dinv_mu<<<2753, 256, 0, stream>>>(tlow, rd, Linv, X, m, cnt, idx, sc, mu,
                                        Xq, Ah, Al, Bh, Bl, a0);
    k_lhat<<<dim3(64, 10), 256, 0, stream>>>(tlow, Linv, Lhat);
    k_linv_fill<<<32, 256, 0, stream>>>(Lhat, Linv, Bh, Bl);
    // Ytout: 128x64 tiles, 25 row-panels x 11 col-tiles; epilogue packs Th/Tl
    k_mfma_nt<<<dim3(NEXT / 64, YPAD / 128), 256, 0, stream>>>(
        Ah, Al, Bh, Bl, Ytout, YPAD, NEXT, NEXT, Th, Tl);
    // gram (first) + G GEMM (128x64 tiles) + at, one dispatch
    k_gv<<<64 + 288 + 512, 256, 0, stream>>>(Th, Tl, rowmap, G, Ytout, mu, sc, at,
                                             h, btil, b0, kinv);
    k_epi<<<dim3(C, Q / 256), 256, 0, stream>>>(G, Ytout, at, a0, h, btil, b0, kinv, sc, out);
}

// Round 13
// 214.093 us; speedup vs baseline: 1.2160x; 1.0150x over previous
//
#include <hip/hip_runtime.h>
#include <hip/hip_bf16.h>

// MetaQDA MAP. D=640, C=64, N=1024, Q=2048, REG=0.3.
// sigma_c*denom = L L^T + U_c J_c U_c^T (rank 18) => Woodbury.
// Round 18: restore R14 (the session's best measured: 214.3us, absmax
// 24576). R12/R13 (LDS pad, LDS-free), R15 (L2 gram), R16 (gram spread),
// R17 (128-tile) all regressed or were neutral; and SQ_LDS_BANK_CONFLICT
// turned out to be an AGGREGATE counter (1.9M cyc / 1024 SIMDs ~ 2k cyc =
// immaterial), which explains every null conflict-fix. k_gv is latency-
// bound at 3 blocks/CU with no remaining safe lever; locking in the best.
// Structure: 7 dispatches; XCD-chunked 64x64 split-bf16 GEMMs (2-barrier
// LDS staging); LDS-staged fp32 gram + 1-wave lockstep GJ; producer-side
// bf16 packing everywhere; right-looking register-resident Linv recurrence.
// Gram stays fp32 (round-6 post-mortem: bf16 Gram -> absmax 1.8e7).

#define D 640
#define C 64
#define NSUP 1024
#define Q 2048
#define KMAX 16
#define R18 18           // Woodbury rank: 1 (m) + 16 (x) + 1 (mu)
#define VROWS (C * R18)  // 1152
#define YROWS 3137       // 2048 Xq + 1024 X + 1 m + 64 mu
#define YPAD 3200
#define NEXT 704         // 640 tilde cols + 64 ip0 cols

typedef __attribute__((ext_vector_type(8))) short bf16x8;
typedef __attribute__((ext_vector_type(4))) float floatx4;

__device__ __forceinline__ unsigned short f2bf(float x) {
    unsigned int u = __float_as_uint(x);
    unsigned int r = u + 0x7FFFu + ((u >> 16) & 1u);
    return (unsigned short)(r >> 16);
}

__device__ __forceinline__ void pack4(const float* vv, unsigned short* hp, unsigned short* lp) {
#pragma unroll
    for (int i = 0; i < 4; ++i) {
        unsigned short hb = f2bf(vv[i]);
        float hf = __uint_as_float((unsigned int)hb << 16);
        hp[i] = hb;
        lp[i] = f2bf(vv[i] - hf);
    }
}

__device__ __forceinline__ void rownorm_body(const float* __restrict__ A, int ld,
                                             float* __restrict__ out, int gw, int lane) {
    const float* row = A + (size_t)gw * ld;
    float s = 0.f;
    for (int d = lane; d < D; d += 64) { float v = row[d]; s += v * v; }
#pragma unroll
    for (int off = 32; off; off >>= 1) s += __shfl_xor(s, off);
    if (lane == 0) out[gw] = s;
}

// bijective chunked XCD swizzle (m204): round-robin pos -> contiguous chunk
__device__ __forceinline__ int xcd_chunk(int orig, int nwg) {
    int q = nwg >> 3, r = nwg & 7;
    int xcd = orig & 7, pos = orig >> 3;
    return (xcd < r) ? xcd * (q + 1) + pos
                     : r * (q + 1) + (xcd - r) * q + pos;
}

// ---------------- setup (block 0) + zero Bh/Bl[0:640] & Ah/Al pad rows ---
#define BZCH (640 * 640 / 8)          // 51200 16B-chunks per B array
#define AZCH (63 * 640 / 8)           // 5040 16B-chunks per A pad region
__global__ void k_setup(const int* __restrict__ y, const float* __restrict__ kappa,
                        const float* __restrict__ nu, const float* __restrict__ diag,
                        int* __restrict__ cnt, int* __restrict__ idx,
                        float* __restrict__ sc, float* __restrict__ rd,
                        int* __restrict__ rowmap,
                        unsigned short* __restrict__ Ah, unsigned short* __restrict__ Al,
                        unsigned short* __restrict__ Bh, unsigned short* __restrict__ Bl) {
    int tid = threadIdx.x;
    if (blockIdx.x > 0) {
        int id = (blockIdx.x - 1) * 256 + tid;
        const uint4 z = {0u, 0u, 0u, 0u};
        if (id < BZCH) ((uint4*)Bh)[id] = z;
        else if (id < 2 * BZCH) ((uint4*)Bl)[id - BZCH] = z;
        else if (id < 2 * BZCH + AZCH) ((uint4*)(Ah + (size_t)YROWS * D))[id - 2 * BZCH] = z;
        else if (id < 2 * BZCH + 2 * AZCH) ((uint4*)(Al + (size_t)YROWS * D))[id - 2 * BZCH - AZCH] = z;
        return;
    }
    __shared__ int lc[C];
    if (tid < C) lc[tid] = 0;
    __syncthreads();
    for (int n = tid; n < NSUP; n += 256) {
        int c = y[n];
        int k = atomicAdd(&lc[c], 1);
        if (k < KMAX) idx[c * KMAX + k] = n;
    }
    __syncthreads();
    for (int d = tid; d < D; d += 256) rd[d] = 1.0f / fabsf(diag[d]);
    if (tid < C) {
        int n = lc[tid]; if (n > KMAX) n = KMAX;
        cnt[tid] = n;
        float kap = fabsf(kappa[0]) + 1e-6f;
        float nuv = fmaxf(nu[0], (float)(D - 1) + 1e-6f);
        float Ncf = (float)n;
        sc[64 + tid]  = Ncf / (kap + Ncf);            // w_c
        sc[128 + tid] = nuv + Ncf + (float)(D + 2);   // denom_c
        sc[192 + tid] = -1.0f / (kap + Ncf);          // J^{-1} last diag
        if (tid == 0) { sc[0] = kap; sc[1] = nuv; }
    }
    __syncthreads();
    for (int i = tid; i < VROWS; i += 256) {
        int c = i / R18, j = i - c * R18;
        int nc = lc[c] < KMAX ? lc[c] : KMAX;
        int rm;
        if (j == 0) rm = Q + NSUP;                       // m~
        else if (j <= KMAX) rm = (j - 1 < nc) ? Q + idx[c * KMAX + j - 1] : -1;
        else rm = Q + NSUP + 1 + c;                      // mu~
        rowmap[i] = rm;
    }
}

// ---------------- fused: dinv + mu + pack(Xq,X,m) + a0 -------------------
__global__ __launch_bounds__(256) void k_dinv_mu(
        const float* __restrict__ tlow, const float* __restrict__ rd,
        float* __restrict__ Linv,
        const float* __restrict__ X, const float* __restrict__ m,
        const int* __restrict__ cnt, const int* __restrict__ idx,
        const float* __restrict__ sc, float* __restrict__ mu,
        const float* __restrict__ Xq,
        unsigned short* __restrict__ Ah, unsigned short* __restrict__ Al,
        unsigned short* __restrict__ Bh, unsigned short* __restrict__ Bl,
        float* __restrict__ a0) {
    __shared__ float Lst[128 * 128];
    int tid = threadIdx.x;
    int bid = blockIdx.x;
    if (bid < 160) {
        int b = bid >> 5;
        int j = ((bid & 31) << 2) + (tid >> 6);
        int lane = tid & 63;
        int bB = b * 128;
        {
            float4 tv[16];
            float rv[16];
#pragma unroll
            for (int u = 0; u < 16; ++u) {
                int e = tid + u * 256;              // e = r*32 + c4/4, covers 128x32
                int c4 = (e & 31) * 4, r = e >> 5;
                tv[u] = *(const float4*)(tlow + (size_t)(bB + r) * D + bB + c4);
                rv[u] = rd[bB + r];
            }
#pragma unroll
            for (int u = 0; u < 16; ++u) {
                int e = tid + u * 256;
                int c4 = (e & 31) * 4, r = e >> 5;
                float vv[4] = {tv[u].x, tv[u].y, tv[u].z, tv[u].w};
#pragma unroll
                for (int t = 0; t < 4; ++t) {
                    int c = c4 + t;
                    float v;
                    if (r == c) v = 1.0f;
                    else if (r > c) v = rv[u] * vv[t];
                    else v = 0.f;
                    Lst[c * 128 + (r ^ (c & 63))] = v;
                }
            }
        }
        __syncthreads();
        float rd0 = rd[bB + lane], rd1 = rd[bB + 64 + lane];
        float acc0 = 0.f, acc1 = 0.f, zz0 = 0.f, zz1 = 0.f;
        for (int i = j; i < 128; ++i) {
            int ri = i >> 6, il = i & 63;
            float av = (ri == 0) ? acc0 : acc1;
            float ai = __shfl(av, il);
            float zi = (i == j) ? __shfl((ri == 0) ? rd0 : rd1, il) : -ai;
            int sw = i & 63;
            float l0 = Lst[i * 128 + (lane ^ sw)];
            float l1 = Lst[i * 128 + 64 + (lane ^ sw)];
            if (lane > i) acc0 += l0 * zi;
            if (64 + lane > i) acc1 += l1 * zi;
            if (lane == i) zz0 = zi;
            if (64 + lane == i) zz1 = zi;
        }
        Linv[(size_t)(bB + lane) * D + bB + j] = zz0;
        Linv[(size_t)(bB + 64 + lane) * D + bB + j] = zz1;
        unsigned short h0 = f2bf(zz0);
        float hf0 = __uint_as_float((unsigned int)h0 << 16);
        Bh[(size_t)(bB + lane) * D + bB + j] = h0;
        Bl[(size_t)(bB + lane) * D + bB + j] = f2bf(zz0 - hf0);
        unsigned short h1 = f2bf(zz1);
        float hf1 = __uint_as_float((unsigned int)h1 << 16);
        Bh[(size_t)(bB + 64 + lane) * D + bB + j] = h1;
        Bl[(size_t)(bB + 64 + lane) * D + bB + j] = f2bf(zz1 - hf1);
    } else if (bid < 320) {
        int u = (bid - 160) * 2 + (tid >> 7);     // 0..319
        int c = u / 5, by = u - c * 5;
        int d = by * 128 + (tid & 127);
        int n = cnt[c];
        float s = 0.f;
        for (int k = 0; k < n; ++k) s += X[(size_t)idx[c * KMAX + k] * D + d];
        float w = sc[64 + c];
        float mean = (n > 0) ? s / (float)n : 0.f;
        float val = (1.f - w) * m[d] + w * mean;
        mu[(size_t)c * D + d] = val;
        unsigned short hb = f2bf(val);
        float hf = __uint_as_float((unsigned int)hb << 16);
        unsigned short lb = f2bf(val - hf);
        Ah[(size_t)(Q + NSUP + 1 + c) * D + d] = hb;   // A row 3073+c
        Al[(size_t)(Q + NSUP + 1 + c) * D + d] = lb;
        Bh[(size_t)(D + c) * D + d] = hb;              // B row 640+c
        Bl[(size_t)(D + c) * D + d] = lb;
    } else if (bid < 2240) {
        int gid = (bid - 320) * 256 + tid;             // rows 0..3071
        int row = gid / 160, c = (gid - row * 160) * 4;
        float4 v = (row < Q) ? *(const float4*)(Xq + (size_t)row * D + c)
                             : *(const float4*)(X + (size_t)(row - Q) * D + c);
        float vv[4] = {v.x, v.y, v.z, v.w};
        ushort4 h, l;
        pack4(vv, (unsigned short*)&h, (unsigned short*)&l);
        *(ushort4*)(Ah + (size_t)row * D + c) = h;
        *(ushort4*)(Al + (size_t)row * D + c) = l;
    } else if (bid == 2240) {
        if (tid < 160) {
            int c = tid * 4;
            float4 v = *(const float4*)(m + c);
            float vv[4] = {v.x, v.y, v.z, v.w};
            ushort4 h, l;
            pack4(vv, (unsigned short*)&h, (unsigned short*)&l);
            *(ushort4*)(Ah + (size_t)(Q + NSUP) * D + c) = h;   // row 3072
            *(ushort4*)(Al + (size_t)(Q + NSUP) * D + c) = l;
        }
    } else {
        int gw = ((bid - 2241) * 256 + tid) >> 6;      // 0..2047
        rownorm_body(Xq, D, a0, gw, tid & 63);
    }
}

// ---------------- Lhat_ik = Dinv_i * L_ik (strict-lower blocks) ----------
__global__ void k_lhat(const float* __restrict__ tlow, const float* __restrict__ Linv,
                       float* __restrict__ Lhat) {
    const int bi_tab[10] = {1, 2, 2, 3, 3, 3, 4, 4, 4, 4};
    const int bk_tab[10] = {0, 0, 1, 0, 1, 2, 0, 1, 2, 3};
    int p = blockIdx.y;
    int bi = bi_tab[p], bk = bk_tab[p];
    int tid = threadIdx.x;
    int c = tid & 127;
    int r = (blockIdx.x << 1) + (tid >> 7);
    const float* drow = Linv + (size_t)(bi * 128 + r) * D + bi * 128;
    const float* lcol = tlow + (size_t)(bi * 128) * D + bk * 128 + c;
    float s = 0.f;
#pragma unroll 4
    for (int t = 0; t < 128; ++t) s += drow[t] * lcol[(size_t)t * D];
    Lhat[(size_t)(bi * 128 + r) * D + bk * 128 + c] = s;
}

// ---------------- Linv off-diag: right-looking strip recurrence ----------
template<int B>
__device__ __forceinline__ void linv_chain(const float* __restrict__ Lhat,
                                           float* __restrict__ Linv,
                                           unsigned short* __restrict__ Bh,
                                           unsigned short* __restrict__ Bl,
                                           float S[4][128][20],
                                           int cB, int tid) {
    const int ty = tid >> 2, tx = tid & 3;   // rows {2ty,2ty+1}, cols 4tx..4tx+3
    const int r0 = 2 * ty;
    float acc[4 - B][2][4];
#pragma unroll
    for (int a = 0; a < 4 - B; ++a)
#pragma unroll
        for (int rr = 0; rr < 2; ++rr)
#pragma unroll
            for (int cc = 0; cc < 4; ++cc) acc[a][rr][cc] = 0.f;
#pragma unroll
    for (int js = 0; js < 4 - B; ++js) {     // contraction block j = B + js
        const int j = B + js;
        for (int k0 = 0; k0 < 128; k0 += 8) {
            float svf[8][4];
#pragma unroll
            for (int u = 0; u < 8; ++u) {
                float4 s4 = *(const float4*)&S[js][k0 + u][tx * 4];
                svf[u][0] = s4.x; svf[u][1] = s4.y; svf[u][2] = s4.z; svf[u][3] = s4.w;
            }
#pragma unroll
            for (int a = js; a < 4 - B; ++a) {   // output block i = B + 1 + a
                const int i = B + 1 + a;
                const float* p0 = Lhat + (size_t)(i * 128 + r0) * D + j * 128 + k0;
                const float* p1 = p0 + D;
                float4 a00 = *(const float4*)(p0);
                float4 a01 = *(const float4*)(p0 + 4);
                float4 a10 = *(const float4*)(p1);
                float4 a11 = *(const float4*)(p1 + 4);
                float ar0[8] = {a00.x, a00.y, a00.z, a00.w, a01.x, a01.y, a01.z, a01.w};
                float ar1[8] = {a10.x, a10.y, a10.z, a10.w, a11.x, a11.y, a11.z, a11.w};
#pragma unroll
                for (int u = 0; u < 8; ++u) {
#pragma unroll
                    for (int cc = 0; cc < 4; ++cc) {
                        acc[a][0][cc] += ar0[u] * svf[u][cc];
                        acc[a][1][cc] += ar1[u] * svf[u][cc];
                    }
                }
            }
        }
        {
            const int i = j + 1;
#pragma unroll
            for (int rr = 0; rr < 2; ++rr) {
                const int r = r0 + rr;
                float vv[4];
#pragma unroll
                for (int cc = 0; cc < 4; ++cc) vv[cc] = -acc[js][rr][cc];
                float4 v = {vv[0], vv[1], vv[2], vv[3]};
                if (js + 1 < 4 - B) *(float4*)&S[js + 1][r][tx * 4] = v;
                *(float4*)(Linv + (size_t)(i * 128 + r) * D + cB + tx * 4) = v;
                ushort4 hh, ll;
                pack4(vv, (unsigned short*)&hh, (unsigned short*)&ll);
                *(ushort4*)(Bh + (size_t)(i * 128 + r) * D + cB + tx * 4) = hh;
                *(ushort4*)(Bl + (size_t)(i * 128 + r) * D + cB + tx * 4) = ll;
            }
        }
        if (js + 1 < 4 - B) __syncthreads();
    }
}

__global__ __launch_bounds__(256) void k_linv_fill(const float* __restrict__ Lhat,
                                                   float* __restrict__ Linv,
                                                   unsigned short* __restrict__ Bh,
                                                   unsigned short* __restrict__ Bl) {
    __shared__ __align__(16) float S[4][128][20];   // 40 KB
    int tid = threadIdx.x;
    int b = blockIdx.x >> 3, strip = blockIdx.x & 7;
    int bB = b * 128, cB = bB + strip * 16;
    {   // load S[0] strip from the Dinv block already in Linv
        int r = tid >> 1, c0 = (tid & 1) * 8;
        const float* src = Linv + (size_t)(bB + r) * D + cB + c0;
        *(float4*)&S[0][r][c0]     = *(const float4*)(src);
        *(float4*)&S[0][r][c0 + 4] = *(const float4*)(src + 4);
    }
    __syncthreads();
    if (b == 0)      linv_chain<0>(Lhat, Linv, Bh, Bl, S, cB, tid);
    else if (b == 1) linv_chain<1>(Lhat, Linv, Bh, Bl, S, cB, tid);
    else if (b == 2) linv_chain<2>(Lhat, Linv, Bh, Bl, S, cB, tid);
    else             linv_chain<3>(Lhat, Linv, Bh, Bl, S, cB, tid);
}

// ---------------- split-bf16 MFMA NT GEMM, 64x64 tile --------------------
// LDS-staged, 2 barriers/step + chunked XCD swizzle (T1).
// If Th != nullptr, epilogue also writes the bf16 split for cols < 640.
__global__ __launch_bounds__(256) void k_mfma_nt(
        const unsigned short* __restrict__ Ah, const unsigned short* __restrict__ Al,
        const unsigned short* __restrict__ Bh, const unsigned short* __restrict__ Bl,
        float* __restrict__ Out, int M, int N, int ldo,
        unsigned short* __restrict__ Th, unsigned short* __restrict__ Tl) {
    __shared__ unsigned short Ah_s[64 * 32], Al_s[64 * 32];
    __shared__ unsigned short Bh_s[64 * 32], Bl_s[64 * 32];
    int tid = threadIdx.x;
    int nbx = gridDim.x, nwg = nbx * gridDim.y;
    int orig = blockIdx.y * nbx + blockIdx.x;
    int wgid = xcd_chunk(orig, nwg);                 // contiguous chunk per XCD
    int rowBase = (wgid / nbx) * 64, colBase = (wgid % nbx) * 64;
    int r = tid >> 2, e = (tid & 3) << 3;
    int gr = rowBase + r;
    int gc = colBase + r;
    bool aok = (gr < M), bok = (gc < N);
    int w = tid >> 6, lane = tid & 63, q = lane >> 4, lr = lane & 15;
    int aoff = (16 * w + lr) * 32 + q * 8;
    const uint4 z4 = {0u, 0u, 0u, 0u};
    floatx4 acc[4] = {{0.f, 0.f, 0.f, 0.f}, {0.f, 0.f, 0.f, 0.f},
                      {0.f, 0.f, 0.f, 0.f}, {0.f, 0.f, 0.f, 0.f}};
    for (int kk = 0; kk < D; kk += 32) {
        uint4 vah = aok ? *(const uint4*)(Ah + (size_t)gr * D + kk + e) : z4;
        uint4 val = aok ? *(const uint4*)(Al + (size_t)gr * D + kk + e) : z4;
        uint4 vbh = bok ? *(const uint4*)(Bh + (size_t)gc * D + kk + e) : z4;
        uint4 vbl = bok ? *(const uint4*)(Bl + (size_t)gc * D + kk + e) : z4;
        __syncthreads();
        *(uint4*)(Ah_s + r * 32 + e) = vah;
        *(uint4*)(Al_s + r * 32 + e) = val;
        *(uint4*)(Bh_s + r * 32 + e) = vbh;
        *(uint4*)(Bl_s + r * 32 + e) = vbl;
        __syncthreads();
        bf16x8 ah = *(const bf16x8*)(Ah_s + aoff);
        bf16x8 al = *(const bf16x8*)(Al_s + aoff);
#pragma unroll
        for (int tt = 0; tt < 4; ++tt) {
            int boff = (16 * tt + lr) * 32 + q * 8;
            bf16x8 bh = *(const bf16x8*)(Bh_s + boff);
            bf16x8 bl = *(const bf16x8*)(Bl_s + boff);
            acc[tt] = __builtin_amdgcn_mfma_f32_16x16x32_bf16(ah, bh, acc[tt], 0, 0, 0);
            acc[tt] = __builtin_amdgcn_mfma_f32_16x16x32_bf16(ah, bl, acc[tt], 0, 0, 0);
            acc[tt] = __builtin_amdgcn_mfma_f32_16x16x32_bf16(al, bh, acc[tt], 0, 0, 0);
        }
    }
#pragma unroll
    for (int tt = 0; tt < 4; ++tt) {
        int gc2 = colBase + 16 * tt + lr;
#pragma unroll
        for (int rg = 0; rg < 4; ++rg) {
            int gr2 = rowBase + 16 * w + q * 4 + rg;
            if (gr2 < M && gc2 < N) {
                float v = acc[tt][rg];
                Out[(size_t)gr2 * ldo + gc2] = v;
                if (Th && gc2 < D) {
                    unsigned short hb = f2bf(v);
                    float hf = __uint_as_float((unsigned int)hb << 16);
                    Th[(size_t)gr2 * D + gc2] = hb;
                    Tl[(size_t)gr2 * D + gc2] = f2bf(v - hf);
                }
            }
        }
    }
}

// ---------------- fused: gram_inv (64) + G GEMM (576) + at (512) ---------
__global__ __launch_bounds__(256) void k_gv(
        const unsigned short* __restrict__ Th, const unsigned short* __restrict__ Tl,
        const int* __restrict__ rowmap, float* __restrict__ G,
        const float* __restrict__ Yt, const float* __restrict__ mu,
        const float* __restrict__ sc, float* __restrict__ at,
        float* __restrict__ h, float* __restrict__ btil,
        float* __restrict__ b0, float* __restrict__ kinv) {
    __shared__ __align__(16) char smem[49344];
    int bid = blockIdx.x, tid = threadIdx.x;
    if (bid < 64) {
        // ---- per-class fp32 Gram (LDS-staged) + 1-wave GJ ----
        float (*sv)[644] = (float(*)[644])smem;                 // 46368 B
        float (*aug)[40] = (float(*)[40])(smem + 46368);        //  2880 B
        int* rmv = (int*)(smem + 46368 + 2880);                 //    72 B
        int c = bid;
        if (tid < R18) rmv[tid] = rowmap[c * R18 + tid];
        __syncthreads();
        {   // batched staging: 12 independent float4 loads per thread
            int rmu[12];
#pragma unroll
            for (int u = 0; u < 12; ++u) {
                int i = tid + u * 256;
                int r = i / 160;
                rmu[u] = (i < R18 * 160) ? rmv[r] : -1;
            }
            float4 buf[12];
            const float4 z = {0.f, 0.f, 0.f, 0.f};
#pragma unroll
            for (int u = 0; u < 12; ++u) {
                int i = tid + u * 256;
                int d4 = (i - (i / 160) * 160) * 4;
                buf[u] = (rmu[u] >= 0) ? *(const float4*)(Yt + (size_t)rmu[u] * NEXT + d4) : z;
            }
#pragma unroll
            for (int u = 0; u < 12; ++u) {
                int i = tid + u * 256;
                if (i < R18 * 160) {
                    int r = i / 160, d4 = (i - r * 160) * 4;
                    *(float4*)&sv[r][d4] = buf[u];
                }
            }
        }
        __syncthreads();
        if (tid < 171) {                 // one thread per (i<=j) pair
            int i = 0, rem = tid;
            while (rem >= R18 - i) { rem -= R18 - i; ++i; }
            int j = i + rem;
            const float* ri = sv[i];
            const float* rj = sv[j];
            float s0 = 0.f, s1 = 0.f, s2 = 0.f, s3 = 0.f;
#pragma unroll 4
            for (int d = 0; d < D; d += 4) {
                float4 a = *(const float4*)(ri + d);
                float4 bb = *(const float4*)(rj + d);
                s0 += a.x * bb.x; s1 += a.y * bb.y;
                s2 += a.z * bb.z; s3 += a.w * bb.w;
            }
            float s = (s0 + s1) + (s2 + s3);
            aug[i][j] = s;
            if (i != j) aug[j][i] = s;
        }
        for (int i2 = tid; i2 < R18 * R18; i2 += 256)   // identity half
            aug[i2 / R18][R18 + i2 % R18] = (i2 / R18 == i2 % R18) ? 1.f : 0.f;
        __syncthreads();
        int w = tid >> 6, lane = tid & 63;
        if (w == 1) {                    // b0 = ||mu_c||^2, concurrent with GJ
            const float* mc = mu + (size_t)c * D;
            float s = 0.f;
            for (int d = lane; d < D; d += 64) { float v = mc[d]; s += v * v; }
#pragma unroll
            for (int off = 32; off; off >>= 1) s += __shfl_xor(s, off);
            if (lane == 0) b0[c] = s;
        }
        if (w == 0) {                    // wave 0: h/btil, diag add, lockstep GJ
            if (lane < R18) h[c * R18 + lane] = aug[lane][R18 - 1];
            if (lane == 0) btil[c] = aug[R18 - 1][R18 - 1];
            volatile float (*va)[40] = (volatile float (*)[40])aug;
            if (lane == 0) va[0][0] += 1.0f / sc[0];
            else if (lane <= KMAX) va[lane][lane] += 1.0f;
            else if (lane == R18 - 1) va[R18 - 1][R18 - 1] += sc[192 + c];
            __threadfence_block();
            for (int p = 0; p < R18; ++p) {
                float v = (lane >= p && lane < R18) ? fabsf(va[lane][p]) : -1.f;
                int bi = lane;
#pragma unroll
                for (int off = 32; off; off >>= 1) {
                    float ov = __shfl_xor(v, off);
                    int oi = __shfl_xor(bi, off);
                    if (ov > v || (ov == v && oi < bi)) { v = ov; bi = oi; }
                }
                float pv = va[bi][p];                    // broadcast read (pre-swap)
                if (lane < 2 * R18) {                    // fused swap + scale
                    float rp = va[bi][lane];
                    if (bi != p) va[bi][lane] = va[p][lane];
                    va[p][lane] = rp / pv;
                }
                __threadfence_block();
                float f  = (lane < R18) ? va[lane][p] : 0.f;
                float pr = (lane < 2 * R18) ? va[p][lane] : 0.f;
#pragma unroll
                for (int it = 0; it < 11; ++it) {
                    int e = lane + it * 64;
                    int r2 = e / 36, cc = e - r2 * 36;
                    float fr = __shfl(f, r2 < R18 ? r2 : 0);
                    float pc = __shfl(pr, cc);
                    if (e < R18 * 2 * R18 && r2 != p) va[r2][cc] -= fr * pc;
                }
                __threadfence_block();
            }
            for (int e = lane; e < R18 * R18; e += 64)
                kinv[(size_t)c * R18 * R18 + e] = va[e / R18][R18 + e % R18];
        }
    } else if (bid < 640) {
        // ---- G GEMM: G[q][c*18+j] = x~q . v~_{c,j} (+ XCD chunk swizzle) ----
        unsigned short* Ah_s = (unsigned short*)smem;            // 4096 B each
        unsigned short* Al_s = (unsigned short*)(smem + 4096);
        unsigned short* Bh_s = (unsigned short*)(smem + 8192);
        unsigned short* Bl_s = (unsigned short*)(smem + 12288);
        int gb0 = bid - 64;
        int gb = xcd_chunk(gb0, 576);    // 576 = 8*72: each XCD owns 4 row-panels
        int rowBase = (gb / 18) * 64, colBase = (gb % 18) * 64;
        int r = tid >> 2, e = (tid & 3) << 3;
        int gr = rowBase + r;
        int gc = colBase + r;
        int br = rowmap[gc];
        int w = tid >> 6, lane = tid & 63, q = lane >> 4, lr = lane & 15;
        int aoff = (16 * w + lr) * 32 + q * 8;
        const uint4 z4 = {0u, 0u, 0u, 0u};
        floatx4 acc[4] = {{0.f, 0.f, 0.f, 0.f}, {0.f, 0.f, 0.f, 0.f},
                          {0.f, 0.f, 0.f, 0.f}, {0.f, 0.f, 0.f, 0.f}};
        for (int kk = 0; kk < D; kk += 32) {
            uint4 vah = *(const uint4*)(Th + (size_t)gr * D + kk + e);
            uint4 val = *(const uint4*)(Tl + (size_t)gr * D + kk + e);
            uint4 vbh = (br >= 0) ? *(const uint4*)(Th + (size_t)br * D + kk + e) : z4;
            uint4 vbl = (br >= 0) ? *(const uint4*)(Tl + (size_t)br * D + kk + e) : z4;
            __syncthreads();
            *(uint4*)(Ah_s + r * 32 + e) = vah;
            *(uint4*)(Al_s + r * 32 + e) = val;
            *(uint4*)(Bh_s + r * 32 + e) = vbh;
            *(uint4*)(Bl_s + r * 32 + e) = vbl;
            __syncthreads();
            bf16x8 ah = *(const bf16x8*)(Ah_s + aoff);
            bf16x8 al = *(const bf16x8*)(Al_s + aoff);
#pragma unroll
            for (int tt = 0; tt < 4; ++tt) {
                int boff = (16 * tt + lr) * 32 + q * 8;
                bf16x8 bh = *(const bf16x8*)(Bh_s + boff);
                bf16x8 bl = *(const bf16x8*)(Bl_s + boff);
                acc[tt] = __builtin_amdgcn_mfma_f32_16x16x32_bf16(ah, bh, acc[tt], 0, 0, 0);
                acc[tt] = __builtin_amdgcn_mfma_f32_16x16x32_bf16(ah, bl, acc[tt], 0, 0, 0);
                acc[tt] = __builtin_amdgcn_mfma_f32_16x16x32_bf16(al, bh, acc[tt], 0, 0, 0);
            }
        }
#pragma unroll
        for (int tt = 0; tt < 4; ++tt) {
            int gc2 = colBase + 16 * tt + lr;
#pragma unroll
            for (int rg = 0; rg < 4; ++rg) {
                int gr2 = rowBase + 16 * w + q * 4 + rg;
                G[(size_t)gr2 * VROWS + gc2] = acc[tt][rg];
            }
        }
    } else {
        // ---- at[q] = ||Ytout_q[0:640]||^2 ----
        int gw = ((bid - 640) * 256 + tid) >> 6;
        rownorm_body(Yt, NEXT, at, gw, tid & 63);
    }
}

// ---------------- epilogue ----------------------------------------------
__global__ void k_epi(const float* __restrict__ G, const float* __restrict__ Yt,
                      const float* __restrict__ at, const float* __restrict__ a0,
                      const float* __restrict__ h, const float* __restrict__ btil,
                      const float* __restrict__ b0, const float* __restrict__ kinv,
                      const float* __restrict__ sc, float* __restrict__ out) {
    __shared__ float lk[R18 * R18], lh[R18];
    __shared__ float ldn, lbt, lb0;
    int c = blockIdx.x, tid = threadIdx.x;
    for (int i = tid; i < R18 * R18; i += 256) lk[i] = kinv[(size_t)c * R18 * R18 + i];
    if (tid < R18) lh[tid] = h[c * R18 + tid];
    if (tid == 0) { ldn = sc[128 + c]; lbt = btil[c]; lb0 = b0[c]; }
    __syncthreads();
    int q = blockIdx.y * 256 + tid;
    const float* Gr = G + (size_t)q * VROWS + c * R18;
    float g[R18];
#pragma unroll
    for (int j = 0; j < R18; ++j) g[j] = Gr[j];
    float ipt = g[R18 - 1];
#pragma unroll
    for (int j = 0; j < R18; ++j) g[j] -= lh[j];
    float corr = 0.f;
#pragma unroll
    for (int i = 0; i < R18; ++i) {
        float s = 0.f;
#pragma unroll
        for (int j = 0; j < R18; ++j) s += lk[i * R18 + j] * g[j];
        corr += g[i] * s;
    }
    float ip0 = Yt[(size_t)q * NEXT + D + c];
    float tt = at[q] - 2.f * ipt + lbt;
    float t0 = a0[q] - 2.f * ip0 + lb0;
    out[(size_t)q * C + c] = -(0.7f * ldn * (tt - corr) + 0.3f * t0);
}

extern "C" void kernel_launch(void* const* d_in, const int* in_sizes, int n_in,
                              void* d_out, int out_size, void* d_ws, size_t ws_size,
                              hipStream_t stream) {
    const float* X     = (const float*)d_in[0];
    const int*   y     = (const int*)d_in[1];
    const float* Xq    = (const float*)d_in[2];
    const float* m     = (const float*)d_in[3];
    const float* kappa = (const float*)d_in[4];
    const float* nu    = (const float*)d_in[5];
    const float* tdiag = (const float*)d_in[6];
    const float* tlow  = (const float*)d_in[7];
    float* out = (float*)d_out;

    char* w = (char*)d_ws;
    auto alloc = [&](size_t bytes) {
        char* p = w;
        w += (bytes + 255) & ~(size_t)255;
        return p;
    };
    int*   cnt    = (int*)alloc(C * 4);
    int*   idx    = (int*)alloc(C * KMAX * 4);
    int*   rowmap = (int*)alloc(VROWS * 4);
    float* sc     = (float*)alloc(256 * 4);
    float* rd     = (float*)alloc(D * 4);
    float* mu     = (float*)alloc((size_t)C * D * 4);
    float* at     = (float*)alloc(Q * 4);
    float* a0     = (float*)alloc(Q * 4);
    float* h      = (float*)alloc(C * R18 * 4);
    float* btil   = (float*)alloc(C * 4);
    float* b0     = (float*)alloc(C * 4);
    float* kinv   = (float*)alloc((size_t)C * R18 * R18 * 4);
    float* Ytout  = (float*)alloc((size_t)YPAD * NEXT * 4);          // 9.0 MB
    unsigned short* Th = (unsigned short*)alloc((size_t)YPAD * D * 2); // 4.1 MB
    unsigned short* Tl = (unsigned short*)alloc((size_t)YPAD * D * 2);
    unsigned short* Bh = (unsigned short*)alloc((size_t)NEXT * D * 2); // 0.9 MB
    unsigned short* Bl = (unsigned short*)alloc((size_t)NEXT * D * 2);
    // region reused by G (all dead before the G GEMM writes):
    char* wmark = w;
    float* Linv = (float*)alloc((size_t)D * D * 4);                  // 1.6 MB
    float* Lhat = (float*)alloc((size_t)D * D * 4);                  // 1.6 MB
    unsigned short* Ah = (unsigned short*)alloc((size_t)YPAD * D * 2); // 4.1 MB
    unsigned short* Al = (unsigned short*)alloc((size_t)YPAD * D * 2);
    w = wmark;
    float* G    = (float*)alloc((size_t)Q * VROWS * 4);              // 9.4 MB

    k_setup<<<441, 256, 0, stream>>>(y, kappa, nu, tdiag, cnt, idx, sc, rd, rowmap,
                                     Ah, Al, Bh, Bl);
    k_dinv_mu<<<2753, 256, 0, stream>>>(tlow, rd, Linv, X, m, cnt, idx, sc, mu,
                                        Xq, Ah, Al, Bh, Bl, a0);
    k_lhat<<<dim3(64, 10), 256, 0, stream>>>(tlow, Linv, Lhat);
    k_linv_fill<<<32, 256, 0, stream>>>(Lhat, Linv, Bh, Bl);
    // Ytout[r][0:640] = tilde rows; [640:704] = x_r . mu_c; epilogue packs Th/Tl
    k_mfma_nt<<<dim3(NEXT / 64, YPAD / 64), 256, 0, stream>>>(
        Ah, Al, Bh, Bl, Ytout, YPAD, NEXT, NEXT, Th, Tl);
    // gram (first) + G GEMM + at, one dispatch
    k_gv<<<1152, 256, 0, stream>>>(Th, Tl, rowmap, G, Ytout, mu, sc, at,
                                   h, btil, b0, kinv);
    k_epi<<<dim3(C, Q / 256), 256, 0, stream>>>(G, Ytout, at, a0, h, btil, b0, kinv, sc, out);
}

// Round 14
// 212.074 us; speedup vs baseline: 1.2276x; 1.0095x over previous
//
#include <hip/hip_runtime.h>
#include <hip/hip_bf16.h>

// MetaQDA MAP. D=640, C=64, N=1024, Q=2048, REG=0.3.
// sigma_c*denom = L L^T + U_c J_c U_c^T (rank 18) => Woodbury.
// Round 19: isolate the dbuf variable from R12's 3-way confound (pad +
// L2-gram + dbuf; pad raised conflicts, L2-gram proven slower+unstable in
// R15 -- dbuf itself never tested alone). This round = EXACT R14 plus
// register-prefetch double-buffered K-loops in both GEMMs (unpadded
// stride-32 LDS, 1 barrier/step, next step's globals issued before the
// barrier). Same MFMA order/values => bitwise-identical (absmax 24576).
// Barrier-order audit: write buf(s%2)@s+2 follows barrier(s+1) which
// collectively follows all MFMA reads of buf(s%2)@s -- race-free.
// Gram stays fp32 + LDS-staged (R10/R15 post-mortems).

#define D 640
#define C 64
#define NSUP 1024
#define Q 2048
#define KMAX 16
#define R18 18           // Woodbury rank: 1 (m) + 16 (x) + 1 (mu)
#define VROWS (C * R18)  // 1152
#define YROWS 3137       // 2048 Xq + 1024 X + 1 m + 64 mu
#define YPAD 3200
#define NEXT 704         // 640 tilde cols + 64 ip0 cols

typedef __attribute__((ext_vector_type(8))) short bf16x8;
typedef __attribute__((ext_vector_type(4))) float floatx4;

__device__ __forceinline__ unsigned short f2bf(float x) {
    unsigned int u = __float_as_uint(x);
    unsigned int r = u + 0x7FFFu + ((u >> 16) & 1u);
    return (unsigned short)(r >> 16);
}

__device__ __forceinline__ void pack4(const float* vv, unsigned short* hp, unsigned short* lp) {
#pragma unroll
    for (int i = 0; i < 4; ++i) {
        unsigned short hb = f2bf(vv[i]);
        float hf = __uint_as_float((unsigned int)hb << 16);
        hp[i] = hb;
        lp[i] = f2bf(vv[i] - hf);
    }
}

__device__ __forceinline__ void rownorm_body(const float* __restrict__ A, int ld,
                                             float* __restrict__ out, int gw, int lane) {
    const float* row = A + (size_t)gw * ld;
    float s = 0.f;
    for (int d = lane; d < D; d += 64) { float v = row[d]; s += v * v; }
#pragma unroll
    for (int off = 32; off; off >>= 1) s += __shfl_xor(s, off);
    if (lane == 0) out[gw] = s;
}

// bijective chunked XCD swizzle (m204): round-robin pos -> contiguous chunk
__device__ __forceinline__ int xcd_chunk(int orig, int nwg) {
    int q = nwg >> 3, r = nwg & 7;
    int xcd = orig & 7, pos = orig >> 3;
    return (xcd < r) ? xcd * (q + 1) + pos
                     : r * (q + 1) + (xcd - r) * q + pos;
}

// ---------------- setup (block 0) + zero Bh/Bl[0:640] & Ah/Al pad rows ---
#define BZCH (640 * 640 / 8)          // 51200 16B-chunks per B array
#define AZCH (63 * 640 / 8)           // 5040 16B-chunks per A pad region
__global__ void k_setup(const int* __restrict__ y, const float* __restrict__ kappa,
                        const float* __restrict__ nu, const float* __restrict__ diag,
                        int* __restrict__ cnt, int* __restrict__ idx,
                        float* __restrict__ sc, float* __restrict__ rd,
                        int* __restrict__ rowmap,
                        unsigned short* __restrict__ Ah, unsigned short* __restrict__ Al,
                        unsigned short* __restrict__ Bh, unsigned short* __restrict__ Bl) {
    int tid = threadIdx.x;
    if (blockIdx.x > 0) {
        int id = (blockIdx.x - 1) * 256 + tid;
        const uint4 z = {0u, 0u, 0u, 0u};
        if (id < BZCH) ((uint4*)Bh)[id] = z;
        else if (id < 2 * BZCH) ((uint4*)Bl)[id - BZCH] = z;
        else if (id < 2 * BZCH + AZCH) ((uint4*)(Ah + (size_t)YROWS * D))[id - 2 * BZCH] = z;
        else if (id < 2 * BZCH + 2 * AZCH) ((uint4*)(Al + (size_t)YROWS * D))[id - 2 * BZCH - AZCH] = z;
        return;
    }
    __shared__ int lc[C];
    if (tid < C) lc[tid] = 0;
    __syncthreads();
    for (int n = tid; n < NSUP; n += 256) {
        int c = y[n];
        int k = atomicAdd(&lc[c], 1);
        if (k < KMAX) idx[c * KMAX + k] = n;
    }
    __syncthreads();
    for (int d = tid; d < D; d += 256) rd[d] = 1.0f / fabsf(diag[d]);
    if (tid < C) {
        int n = lc[tid]; if (n > KMAX) n = KMAX;
        cnt[tid] = n;
        float kap = fabsf(kappa[0]) + 1e-6f;
        float nuv = fmaxf(nu[0], (float)(D - 1) + 1e-6f);
        float Ncf = (float)n;
        sc[64 + tid]  = Ncf / (kap + Ncf);            // w_c
        sc[128 + tid] = nuv + Ncf + (float)(D + 2);   // denom_c
        sc[192 + tid] = -1.0f / (kap + Ncf);          // J^{-1} last diag
        if (tid == 0) { sc[0] = kap; sc[1] = nuv; }
    }
    __syncthreads();
    for (int i = tid; i < VROWS; i += 256) {
        int c = i / R18, j = i - c * R18;
        int nc = lc[c] < KMAX ? lc[c] : KMAX;
        int rm;
        if (j == 0) rm = Q + NSUP;                       // m~
        else if (j <= KMAX) rm = (j - 1 < nc) ? Q + idx[c * KMAX + j - 1] : -1;
        else rm = Q + NSUP + 1 + c;                      // mu~
        rowmap[i] = rm;
    }
}

// ---------------- fused: dinv + mu + pack(Xq,X,m) + a0 -------------------
__global__ __launch_bounds__(256) void k_dinv_mu(
        const float* __restrict__ tlow, const float* __restrict__ rd,
        float* __restrict__ Linv,
        const float* __restrict__ X, const float* __restrict__ m,
        const int* __restrict__ cnt, const int* __restrict__ idx,
        const float* __restrict__ sc, float* __restrict__ mu,
        const float* __restrict__ Xq,
        unsigned short* __restrict__ Ah, unsigned short* __restrict__ Al,
        unsigned short* __restrict__ Bh, unsigned short* __restrict__ Bl,
        float* __restrict__ a0) {
    __shared__ float Lst[128 * 128];
    int tid = threadIdx.x;
    int bid = blockIdx.x;
    if (bid < 160) {
        int b = bid >> 5;
        int j = ((bid & 31) << 2) + (tid >> 6);
        int lane = tid & 63;
        int bB = b * 128;
        {
            float4 tv[16];
            float rv[16];
#pragma unroll
            for (int u = 0; u < 16; ++u) {
                int e = tid + u * 256;              // e = r*32 + c4/4, covers 128x32
                int c4 = (e & 31) * 4, r = e >> 5;
                tv[u] = *(const float4*)(tlow + (size_t)(bB + r) * D + bB + c4);
                rv[u] = rd[bB + r];
            }
#pragma unroll
            for (int u = 0; u < 16; ++u) {
                int e = tid + u * 256;
                int c4 = (e & 31) * 4, r = e >> 5;
                float vv[4] = {tv[u].x, tv[u].y, tv[u].z, tv[u].w};
#pragma unroll
                for (int t = 0; t < 4; ++t) {
                    int c = c4 + t;
                    float v;
                    if (r == c) v = 1.0f;
                    else if (r > c) v = rv[u] * vv[t];
                    else v = 0.f;
                    Lst[c * 128 + (r ^ (c & 63))] = v;
                }
            }
        }
        __syncthreads();
        float rd0 = rd[bB + lane], rd1 = rd[bB + 64 + lane];
        float acc0 = 0.f, acc1 = 0.f, zz0 = 0.f, zz1 = 0.f;
        for (int i = j; i < 128; ++i) {
            int ri = i >> 6, il = i & 63;
            float av = (ri == 0) ? acc0 : acc1;
            float ai = __shfl(av, il);
            float zi = (i == j) ? __shfl((ri == 0) ? rd0 : rd1, il) : -ai;
            int sw = i & 63;
            float l0 = Lst[i * 128 + (lane ^ sw)];
            float l1 = Lst[i * 128 + 64 + (lane ^ sw)];
            if (lane > i) acc0 += l0 * zi;
            if (64 + lane > i) acc1 += l1 * zi;
            if (lane == i) zz0 = zi;
            if (64 + lane == i) zz1 = zi;
        }
        Linv[(size_t)(bB + lane) * D + bB + j] = zz0;
        Linv[(size_t)(bB + 64 + lane) * D + bB + j] = zz1;
        unsigned short h0 = f2bf(zz0);
        float hf0 = __uint_as_float((unsigned int)h0 << 16);
        Bh[(size_t)(bB + lane) * D + bB + j] = h0;
        Bl[(size_t)(bB + lane) * D + bB + j] = f2bf(zz0 - hf0);
        unsigned short h1 = f2bf(zz1);
        float hf1 = __uint_as_float((unsigned int)h1 << 16);
        Bh[(size_t)(bB + 64 + lane) * D + bB + j] = h1;
        Bl[(size_t)(bB + 64 + lane) * D + bB + j] = f2bf(zz1 - hf1);
    } else if (bid < 320) {
        int u = (bid - 160) * 2 + (tid >> 7);     // 0..319
        int c = u / 5, by = u - c * 5;
        int d = by * 128 + (tid & 127);
        int n = cnt[c];
        float s = 0.f;
        for (int k = 0; k < n; ++k) s += X[(size_t)idx[c * KMAX + k] * D + d];
        float w = sc[64 + c];
        float mean = (n > 0) ? s / (float)n : 0.f;
        float val = (1.f - w) * m[d] + w * mean;
        mu[(size_t)c * D + d] = val;
        unsigned short hb = f2bf(val);
        float hf = __uint_as_float((unsigned int)hb << 16);
        unsigned short lb = f2bf(val - hf);
        Ah[(size_t)(Q + NSUP + 1 + c) * D + d] = hb;   // A row 3073+c
        Al[(size_t)(Q + NSUP + 1 + c) * D + d] = lb;
        Bh[(size_t)(D + c) * D + d] = hb;              // B row 640+c
        Bl[(size_t)(D + c) * D + d] = lb;
    } else if (bid < 2240) {
        int gid = (bid - 320) * 256 + tid;             // rows 0..3071
        int row = gid / 160, c = (gid - row * 160) * 4;
        float4 v = (row < Q) ? *(const float4*)(Xq + (size_t)row * D + c)
                             : *(const float4*)(X + (size_t)(row - Q) * D + c);
        float vv[4] = {v.x, v.y, v.z, v.w};
        ushort4 h, l;
        pack4(vv, (unsigned short*)&h, (unsigned short*)&l);
        *(ushort4*)(Ah + (size_t)row * D + c) = h;
        *(ushort4*)(Al + (size_t)row * D + c) = l;
    } else if (bid == 2240) {
        if (tid < 160) {
            int c = tid * 4;
            float4 v = *(const float4*)(m + c);
            float vv[4] = {v.x, v.y, v.z, v.w};
            ushort4 h, l;
            pack4(vv, (unsigned short*)&h, (unsigned short*)&l);
            *(ushort4*)(Ah + (size_t)(Q + NSUP) * D + c) = h;   // row 3072
            *(ushort4*)(Al + (size_t)(Q + NSUP) * D + c) = l;
        }
    } else {
        int gw = ((bid - 2241) * 256 + tid) >> 6;      // 0..2047
        rownorm_body(Xq, D, a0, gw, tid & 63);
    }
}

// ---------------- Lhat_ik = Dinv_i * L_ik (strict-lower blocks) ----------
__global__ void k_lhat(const float* __restrict__ tlow, const float* __restrict__ Linv,
                       float* __restrict__ Lhat) {
    const int bi_tab[10] = {1, 2, 2, 3, 3, 3, 4, 4, 4, 4};
    const int bk_tab[10] = {0, 0, 1, 0, 1, 2, 0, 1, 2, 3};
    int p = blockIdx.y;
    int bi = bi_tab[p], bk = bk_tab[p];
    int tid = threadIdx.x;
    int c = tid & 127;
    int r = (blockIdx.x << 1) + (tid >> 7);
    const float* drow = Linv + (size_t)(bi * 128 + r) * D + bi * 128;
    const float* lcol = tlow + (size_t)(bi * 128) * D + bk * 128 + c;
    float s = 0.f;
#pragma unroll 4
    for (int t = 0; t < 128; ++t) s += drow[t] * lcol[(size_t)t * D];
    Lhat[(size_t)(bi * 128 + r) * D + bk * 128 + c] = s;
}

// ---------------- Linv off-diag: right-looking strip recurrence ----------
template<int B>
__device__ __forceinline__ void linv_chain(const float* __restrict__ Lhat,
                                           float* __restrict__ Linv,
                                           unsigned short* __restrict__ Bh,
                                           unsigned short* __restrict__ Bl,
                                           float S[4][128][20],
                                           int cB, int tid) {
    const int ty = tid >> 2, tx = tid & 3;   // rows {2ty,2ty+1}, cols 4tx..4tx+3
    const int r0 = 2 * ty;
    float acc[4 - B][2][4];
#pragma unroll
    for (int a = 0; a < 4 - B; ++a)
#pragma unroll
        for (int rr = 0; rr < 2; ++rr)
#pragma unroll
            for (int cc = 0; cc < 4; ++cc) acc[a][rr][cc] = 0.f;
#pragma unroll
    for (int js = 0; js < 4 - B; ++js) {     // contraction block j = B + js
        const int j = B + js;
        for (int k0 = 0; k0 < 128; k0 += 8) {
            float svf[8][4];
#pragma unroll
            for (int u = 0; u < 8; ++u) {
                float4 s4 = *(const float4*)&S[js][k0 + u][tx * 4];
                svf[u][0] = s4.x; svf[u][1] = s4.y; svf[u][2] = s4.z; svf[u][3] = s4.w;
            }
#pragma unroll
            for (int a = js; a < 4 - B; ++a) {   // output block i = B + 1 + a
                const int i = B + 1 + a;
                const float* p0 = Lhat + (size_t)(i * 128 + r0) * D + j * 128 + k0;
                const float* p1 = p0 + D;
                float4 a00 = *(const float4*)(p0);
                float4 a01 = *(const float4*)(p0 + 4);
                float4 a10 = *(const float4*)(p1);
                float4 a11 = *(const float4*)(p1 + 4);
                float ar0[8] = {a00.x, a00.y, a00.z, a00.w, a01.x, a01.y, a01.z, a01.w};
                float ar1[8] = {a10.x, a10.y, a10.z, a10.w, a11.x, a11.y, a11.z, a11.w};
#pragma unroll
                for (int u = 0; u < 8; ++u) {
#pragma unroll
                    for (int cc = 0; cc < 4; ++cc) {
                        acc[a][0][cc] += ar0[u] * svf[u][cc];
                        acc[a][1][cc] += ar1[u] * svf[u][cc];
                    }
                }
            }
        }
        {
            const int i = j + 1;
#pragma unroll
            for (int rr = 0; rr < 2; ++rr) {
                const int r = r0 + rr;
                float vv[4];
#pragma unroll
                for (int cc = 0; cc < 4; ++cc) vv[cc] = -acc[js][rr][cc];
                float4 v = {vv[0], vv[1], vv[2], vv[3]};
                if (js + 1 < 4 - B) *(float4*)&S[js + 1][r][tx * 4] = v;
                *(float4*)(Linv + (size_t)(i * 128 + r) * D + cB + tx * 4) = v;
                ushort4 hh, ll;
                pack4(vv, (unsigned short*)&hh, (unsigned short*)&ll);
                *(ushort4*)(Bh + (size_t)(i * 128 + r) * D + cB + tx * 4) = hh;
                *(ushort4*)(Bl + (size_t)(i * 128 + r) * D + cB + tx * 4) = ll;
            }
        }
        if (js + 1 < 4 - B) __syncthreads();
    }
}

__global__ __launch_bounds__(256) void k_linv_fill(const float* __restrict__ Lhat,
                                                   float* __restrict__ Linv,
                                                   unsigned short* __restrict__ Bh,
                                                   unsigned short* __restrict__ Bl) {
    __shared__ __align__(16) float S[4][128][20];   // 40 KB
    int tid = threadIdx.x;
    int b = blockIdx.x >> 3, strip = blockIdx.x & 7;
    int bB = b * 128, cB = bB + strip * 16;
    {   // load S[0] strip from the Dinv block already in Linv
        int r = tid >> 1, c0 = (tid & 1) * 8;
        const float* src = Linv + (size_t)(bB + r) * D + cB + c0;
        *(float4*)&S[0][r][c0]     = *(const float4*)(src);
        *(float4*)&S[0][r][c0 + 4] = *(const float4*)(src + 4);
    }
    __syncthreads();
    if (b == 0)      linv_chain<0>(Lhat, Linv, Bh, Bl, S, cB, tid);
    else if (b == 1) linv_chain<1>(Lhat, Linv, Bh, Bl, S, cB, tid);
    else if (b == 2) linv_chain<2>(Lhat, Linv, Bh, Bl, S, cB, tid);
    else             linv_chain<3>(Lhat, Linv, Bh, Bl, S, cB, tid);
}

// ---------------- split-bf16 MFMA NT GEMM, 64x64 tile, dbuf --------------
// Register-prefetch double-buffered K-loop: next step's globals issue
// before the barrier; ONE barrier/step. Unpadded stride-32 LDS. Chunked
// XCD swizzle (T1). If Th != nullptr, epilogue packs cols < 640.
__global__ __launch_bounds__(256) void k_mfma_nt(
        const unsigned short* __restrict__ Ah, const unsigned short* __restrict__ Al,
        const unsigned short* __restrict__ Bh, const unsigned short* __restrict__ Bl,
        float* __restrict__ Out, int M, int N, int ldo,
        unsigned short* __restrict__ Th, unsigned short* __restrict__ Tl) {
    __shared__ unsigned short SB[2][4][64 * 32];     // 32768 B
    int tid = threadIdx.x;
    int nbx = gridDim.x, nwg = nbx * gridDim.y;
    int orig = blockIdx.y * nbx + blockIdx.x;
    int wgid = xcd_chunk(orig, nwg);                 // contiguous chunk per XCD
    int rowBase = (wgid / nbx) * 64, colBase = (wgid % nbx) * 64;
    int r = tid >> 2, e = (tid & 3) << 3;
    int gr = rowBase + r;
    int gc = colBase + r;
    bool aok = (gr < M), bok = (gc < N);
    int w = tid >> 6, lane = tid & 63, q = lane >> 4, lr = lane & 15;
    int aoff = (16 * w + lr) * 32 + q * 8;
    int wr = r * 32 + e;
    const uint4 z4 = {0u, 0u, 0u, 0u};
    floatx4 acc[4] = {{0.f, 0.f, 0.f, 0.f}, {0.f, 0.f, 0.f, 0.f},
                      {0.f, 0.f, 0.f, 0.f}, {0.f, 0.f, 0.f, 0.f}};
    uint4 vah, val, vbh, vbl;
#define LOADK(kk) { \
        vah = aok ? *(const uint4*)(Ah + (size_t)gr * D + (kk) + e) : z4; \
        val = aok ? *(const uint4*)(Al + (size_t)gr * D + (kk) + e) : z4; \
        vbh = bok ? *(const uint4*)(Bh + (size_t)gc * D + (kk) + e) : z4; \
        vbl = bok ? *(const uint4*)(Bl + (size_t)gc * D + (kk) + e) : z4; }
    LOADK(0);
    for (int step = 0; step < D / 32; ++step) {
        int cur = step & 1;
        *(uint4*)(&SB[cur][0][wr]) = vah;
        *(uint4*)(&SB[cur][1][wr]) = val;
        *(uint4*)(&SB[cur][2][wr]) = vbh;
        *(uint4*)(&SB[cur][3][wr]) = vbl;
        if (step + 1 < D / 32) LOADK((step + 1) * 32);
        __syncthreads();
        bf16x8 ah = *(const bf16x8*)(&SB[cur][0][aoff]);
        bf16x8 al = *(const bf16x8*)(&SB[cur][1][aoff]);
#pragma unroll
        for (int tt = 0; tt < 4; ++tt) {
            int boff = (16 * tt + lr) * 32 + q * 8;
            bf16x8 bh = *(const bf16x8*)(&SB[cur][2][boff]);
            bf16x8 bl = *(const bf16x8*)(&SB[cur][3][boff]);
            acc[tt] = __builtin_amdgcn_mfma_f32_16x16x32_bf16(ah, bh, acc[tt], 0, 0, 0);
            acc[tt] = __builtin_amdgcn_mfma_f32_16x16x32_bf16(ah, bl, acc[tt], 0, 0, 0);
            acc[tt] = __builtin_amdgcn_mfma_f32_16x16x32_bf16(al, bh, acc[tt], 0, 0, 0);
        }
    }
#undef LOADK
#pragma unroll
    for (int tt = 0; tt < 4; ++tt) {
        int gc2 = colBase + 16 * tt + lr;
#pragma unroll
        for (int rg = 0; rg < 4; ++rg) {
            int gr2 = rowBase + 16 * w + q * 4 + rg;
            if (gr2 < M && gc2 < N) {
                float v = acc[tt][rg];
                Out[(size_t)gr2 * ldo + gc2] = v;
                if (Th && gc2 < D) {
                    unsigned short hb = f2bf(v);
                    float hf = __uint_as_float((unsigned int)hb << 16);
                    Th[(size_t)gr2 * D + gc2] = hb;
                    Tl[(size_t)gr2 * D + gc2] = f2bf(v - hf);
                }
            }
        }
    }
}

// ---------------- fused: gram_inv (64) + G GEMM (576) + at (512) ---------
__global__ __launch_bounds__(256) void k_gv(
        const unsigned short* __restrict__ Th, const unsigned short* __restrict__ Tl,
        const int* __restrict__ rowmap, float* __restrict__ G,
        const float* __restrict__ Yt, const float* __restrict__ mu,
        const float* __restrict__ sc, float* __restrict__ at,
        float* __restrict__ h, float* __restrict__ btil,
        float* __restrict__ b0, float* __restrict__ kinv) {
    __shared__ __align__(16) char smem[49344];
    int bid = blockIdx.x, tid = threadIdx.x;
    if (bid < 64) {
        // ---- per-class fp32 Gram (LDS-staged) + 1-wave GJ ----
        float (*sv)[644] = (float(*)[644])smem;                 // 46368 B
        float (*aug)[40] = (float(*)[40])(smem + 46368);        //  2880 B
        int* rmv = (int*)(smem + 46368 + 2880);                 //    72 B
        int c = bid;
        if (tid < R18) rmv[tid] = rowmap[c * R18 + tid];
        __syncthreads();
        {   // batched staging: 12 independent float4 loads per thread
            int rmu[12];
#pragma unroll
            for (int u = 0; u < 12; ++u) {
                int i = tid + u * 256;
                int r = i / 160;
                rmu[u] = (i < R18 * 160) ? rmv[r] : -1;
            }
            float4 buf[12];
            const float4 z = {0.f, 0.f, 0.f, 0.f};
#pragma unroll
            for (int u = 0; u < 12; ++u) {
                int i = tid + u * 256;
                int d4 = (i - (i / 160) * 160) * 4;
                buf[u] = (rmu[u] >= 0) ? *(const float4*)(Yt + (size_t)rmu[u] * NEXT + d4) : z;
            }
#pragma unroll
            for (int u = 0; u < 12; ++u) {
                int i = tid + u * 256;
                if (i < R18 * 160) {
                    int r = i / 160, d4 = (i - r * 160) * 4;
                    *(float4*)&sv[r][d4] = buf[u];
                }
            }
        }
        __syncthreads();
        if (tid < 171) {                 // one thread per (i<=j) pair
            int i = 0, rem = tid;
            while (rem >= R18 - i) { rem -= R18 - i; ++i; }
            int j = i + rem;
            const float* ri = sv[i];
            const float* rj = sv[j];
            float s0 = 0.f, s1 = 0.f, s2 = 0.f, s3 = 0.f;
#pragma unroll 4
            for (int d = 0; d < D; d += 4) {
                float4 a = *(const float4*)(ri + d);
                float4 bb = *(const float4*)(rj + d);
                s0 += a.x * bb.x; s1 += a.y * bb.y;
                s2 += a.z * bb.z; s3 += a.w * bb.w;
            }
            float s = (s0 + s1) + (s2 + s3);
            aug[i][j] = s;
            if (i != j) aug[j][i] = s;
        }
        for (int i2 = tid; i2 < R18 * R18; i2 += 256)   // identity half
            aug[i2 / R18][R18 + i2 % R18] = (i2 / R18 == i2 % R18) ? 1.f : 0.f;
        __syncthreads();
        int w = tid >> 6, lane = tid & 63;
        if (w == 1) {                    // b0 = ||mu_c||^2, concurrent with GJ
            const float* mc = mu + (size_t)c * D;
            float s = 0.f;
            for (int d = lane; d < D; d += 64) { float v = mc[d]; s += v * v; }
#pragma unroll
            for (int off = 32; off; off >>= 1) s += __shfl_xor(s, off);
            if (lane == 0) b0[c] = s;
        }
        if (w == 0) {                    // wave 0: h/btil, diag add, lockstep GJ
            if (lane < R18) h[c * R18 + lane] = aug[lane][R18 - 1];
            if (lane == 0) btil[c] = aug[R18 - 1][R18 - 1];
            volatile float (*va)[40] = (volatile float (*)[40])aug;
            if (lane == 0) va[0][0] += 1.0f / sc[0];
            else if (lane <= KMAX) va[lane][lane] += 1.0f;
            else if (lane == R18 - 1) va[R18 - 1][R18 - 1] += sc[192 + c];
            __threadfence_block();
            for (int p = 0; p < R18; ++p) {
                float v = (lane >= p && lane < R18) ? fabsf(va[lane][p]) : -1.f;
                int bi = lane;
#pragma unroll
                for (int off = 32; off; off >>= 1) {
                    float ov = __shfl_xor(v, off);
                    int oi = __shfl_xor(bi, off);
                    if (ov > v || (ov == v && oi < bi)) { v = ov; bi = oi; }
                }
                float pv = va[bi][p];                    // broadcast read (pre-swap)
                if (lane < 2 * R18) {                    // fused swap + scale
                    float rp = va[bi][lane];
                    if (bi != p) va[bi][lane] = va[p][lane];
                    va[p][lane] = rp / pv;
                }
                __threadfence_block();
                float f  = (lane < R18) ? va[lane][p] : 0.f;
                float pr = (lane < 2 * R18) ? va[p][lane] : 0.f;
#pragma unroll
                for (int it = 0; it < 11; ++it) {
                    int e = lane + it * 64;
                    int r2 = e / 36, cc = e - r2 * 36;
                    float fr = __shfl(f, r2 < R18 ? r2 : 0);
                    float pc = __shfl(pr, cc);
                    if (e < R18 * 2 * R18 && r2 != p) va[r2][cc] -= fr * pc;
                }
                __threadfence_block();
            }
            for (int e = lane; e < R18 * R18; e += 64)
                kinv[(size_t)c * R18 * R18 + e] = va[e / R18][R18 + e % R18];
        }
    } else if (bid < 640) {
        // ---- G GEMM: dbuf K-loop + XCD chunk swizzle ----
        unsigned short (*SB)[4][64 * 32] = (unsigned short (*)[4][64 * 32])smem;  // 32768 B
        int gb0 = bid - 64;
        int gb = xcd_chunk(gb0, 576);    // 576 = 8*72: each XCD owns 4 row-panels
        int rowBase = (gb / 18) * 64, colBase = (gb % 18) * 64;
        int r = tid >> 2, e = (tid & 3) << 3;
        int gr = rowBase + r;
        int gc = colBase + r;
        int br = rowmap[gc];
        int w = tid >> 6, lane = tid & 63, q = lane >> 4, lr = lane & 15;
        int aoff = (16 * w + lr) * 32 + q * 8;
        int wr = r * 32 + e;
        const uint4 z4 = {0u, 0u, 0u, 0u};
        floatx4 acc[4] = {{0.f, 0.f, 0.f, 0.f}, {0.f, 0.f, 0.f, 0.f},
                          {0.f, 0.f, 0.f, 0.f}, {0.f, 0.f, 0.f, 0.f}};
        uint4 vah, val, vbh, vbl;
#define LOADG(kk) { \
            vah = *(const uint4*)(Th + (size_t)gr * D + (kk) + e); \
            val = *(const uint4*)(Tl + (size_t)gr * D + (kk) + e); \
            vbh = (br >= 0) ? *(const uint4*)(Th + (size_t)br * D + (kk) + e) : z4; \
            vbl = (br >= 0) ? *(const uint4*)(Tl + (size_t)br * D + (kk) + e) : z4; }
        LOADG(0);
        for (int step = 0; step < D / 32; ++step) {
            int cur = step & 1;
            *(uint4*)(&SB[cur][0][wr]) = vah;
            *(uint4*)(&SB[cur][1][wr]) = val;
            *(uint4*)(&SB[cur][2][wr]) = vbh;
            *(uint4*)(&SB[cur][3][wr]) = vbl;
            if (step + 1 < D / 32) LOADG((step + 1) * 32);
            __syncthreads();
            bf16x8 ah = *(const bf16x8*)(&SB[cur][0][aoff]);
            bf16x8 al = *(const bf16x8*)(&SB[cur][1][aoff]);
#pragma unroll
            for (int tt = 0; tt < 4; ++tt) {
                int boff = (16 * tt + lr) * 32 + q * 8;
                bf16x8 bh = *(const bf16x8*)(&SB[cur][2][boff]);
                bf16x8 bl = *(const bf16x8*)(&SB[cur][3][boff]);
                acc[tt] = __builtin_amdgcn_mfma_f32_16x16x32_bf16(ah, bh, acc[tt], 0, 0, 0);
                acc[tt] = __builtin_amdgcn_mfma_f32_16x16x32_bf16(ah, bl, acc[tt], 0, 0, 0);
                acc[tt] = __builtin_amdgcn_mfma_f32_16x16x32_bf16(al, bh, acc[tt], 0, 0, 0);
            }
        }
#undef LOADG
#pragma unroll
        for (int tt = 0; tt < 4; ++tt) {
            int gc2 = colBase + 16 * tt + lr;
#pragma unroll
            for (int rg = 0; rg < 4; ++rg) {
                int gr2 = rowBase + 16 * w + q * 4 + rg;
                G[(size_t)gr2 * VROWS + gc2] = acc[tt][rg];
            }
        }
    } else {
        // ---- at[q] = ||Ytout_q[0:640]||^2 ----
        int gw = ((bid - 640) * 256 + tid) >> 6;
        rownorm_body(Yt, NEXT, at, gw, tid & 63);
    }
}

// ---------------- epilogue ----------------------------------------------
__global__ void k_epi(const float* __restrict__ G, const float* __restrict__ Yt,
                      const float* __restrict__ at, const float* __restrict__ a0,
                      const float* __restrict__ h, const float* __restrict__ btil,
                      const float* __restrict__ b0, const float* __restrict__ kinv,
                      const float* __restrict__ sc, float* __restrict__ out) {
    __shared__ float lk[R18 * R18], lh[R18];
    __shared__ float ldn, lbt, lb0;
    int c = blockIdx.x, tid = threadIdx.x;
    for (int i = tid; i < R18 * R18; i += 256) lk[i] = kinv[(size_t)c * R18 * R18 + i];
    if (tid < R18) lh[tid] = h[c * R18 + tid];
    if (tid == 0) { ldn = sc[128 + c]; lbt = btil[c]; lb0 = b0[c]; }
    __syncthreads();
    int q = blockIdx.y * 256 + tid;
    const float* Gr = G + (size_t)q * VROWS + c * R18;
    float g[R18];
#pragma unroll
    for (int j = 0; j < R18; ++j) g[j] = Gr[j];
    float ipt = g[R18 - 1];
#pragma unroll
    for (int j = 0; j < R18; ++j) g[j] -= lh[j];
    float corr = 0.f;
#pragma unroll
    for (int i = 0; i < R18; ++i) {
        float s = 0.f;
#pragma unroll
        for (int j = 0; j < R18; ++j) s += lk[i * R18 + j] * g[j];
        corr += g[i] * s;
    }
    float ip0 = Yt[(size_t)q * NEXT + D + c];
    float tt = at[q] - 2.f * ipt + lbt;
    float t0 = a0[q] - 2.f * ip0 + lb0;
    out[(size_t)q * C + c] = -(0.7f * ldn * (tt - corr) + 0.3f * t0);
}

extern "C" void kernel_launch(void* const* d_in, const int* in_sizes, int n_in,
                              void* d_out, int out_size, void* d_ws, size_t ws_size,
                              hipStream_t stream) {
    const float* X     = (const float*)d_in[0];
    const int*   y     = (const int*)d_in[1];
    const float* Xq    = (const float*)d_in[2];
    const float* m     = (const float*)d_in[3];
    const float* kappa = (const float*)d_in[4];
    const float* nu    = (const float*)d_in[5];
    const float* tdiag = (const float*)d_in[6];
    const float* tlow  = (const float*)d_in[7];
    float* out = (float*)d_out;

    char* w = (char*)d_ws;
    auto alloc = [&](size_t bytes) {
        char* p = w;
        w += (bytes + 255) & ~(size_t)255;
        return p;
    };
    int*   cnt    = (int*)alloc(C * 4);
    int*   idx    = (int*)alloc(C * KMAX * 4);
    int*   rowmap = (int*)alloc(VROWS * 4);
    float* sc     = (float*)alloc(256 * 4);
    float* rd     = (float*)alloc(D * 4);
    float* mu     = (float*)alloc((size_t)C * D * 4);
    float* at     = (float*)alloc(Q * 4);
    float* a0     = (float*)alloc(Q * 4);
    float* h      = (float*)alloc(C * R18 * 4);
    float* btil   = (float*)alloc(C * 4);
    float* b0     = (float*)alloc(C * 4);
    float* kinv   = (float*)alloc((size_t)C * R18 * R18 * 4);
    float* Ytout  = (float*)alloc((size_t)YPAD * NEXT * 4);          // 9.0 MB
    unsigned short* Th = (unsigned short*)alloc((size_t)YPAD * D * 2); // 4.1 MB
    unsigned short* Tl = (unsigned short*)alloc((size_t)YPAD * D * 2);
    unsigned short* Bh = (unsigned short*)alloc((size_t)NEXT * D * 2); // 0.9 MB
    unsigned short* Bl = (unsigned short*)alloc((size_t)NEXT * D * 2);
    // region reused by G (all dead before the G GEMM writes):
    char* wmark = w;
    float* Linv = (float*)alloc((size_t)D * D * 4);                  // 1.6 MB
    float* Lhat = (float*)alloc((size_t)D * D * 4);                  // 1.6 MB
    unsigned short* Ah = (unsigned short*)alloc((size_t)YPAD * D * 2); // 4.1 MB
    unsigned short* Al = (unsigned short*)alloc((size_t)YPAD * D * 2);
    w = wmark;
    float* G    = (float*)alloc((size_t)Q * VROWS * 4);              // 9.4 MB

    k_setup<<<441, 256, 0, stream>>>(y, kappa, nu, tdiag, cnt, idx, sc, rd, rowmap,
                                     Ah, Al, Bh, Bl);
    k_dinv_mu<<<2753, 256, 0, stream>>>(tlow, rd, Linv, X, m, cnt, idx, sc, mu,
                                        Xq, Ah, Al, Bh, Bl, a0);
    k_lhat<<<dim3(64, 10), 256, 0, stream>>>(tlow, Linv, Lhat);
    k_linv_fill<<<32, 256, 0, stream>>>(Lhat, Linv, Bh, Bl);
    // Ytout[r][0:640] = tilde rows; [640:704] = x_r . mu_c; epilogue packs Th/Tl
    k_mfma_nt<<<dim3(NEXT / 64, YPAD / 64), 256, 0, stream>>>(
        Ah, Al, Bh, Bl, Ytout, YPAD, NEXT, NEXT, Th, Tl);
    // gram (first) + G GEMM + at, one dispatch
    k_gv<<<1152, 256, 0, stream>>>(Th, Tl, rowmap, G, Ytout, mu, sc, at,
                                   h, btil, b0, kinv);
    k_epi<<<dim3(C, Q / 256), 256, 0, stream>>>(G, Ytout, at, a0, h, btil, b0, kinv, sc, out);
}